// Round 4
// baseline (216.959 us; speedup 1.0000x reference)
//
#include <hip/hip_runtime.h>
#include <hip/hip_bf16.h>
#include <math.h>

#define BGR  256      // graphs
#define NN   400      // nodes per graph (stage 1)
#define EPG  6400     // edges per graph

// ---------------------------------------------------------------------------
// GEMM: H[M x 64] = X[M x K] @ W[K x 64], M multiple of 64, f32.
// ---------------------------------------------------------------------------
template<int K>
__global__ __launch_bounds__(256) void gemm64(const float* __restrict__ X,
                                              const float* __restrict__ W,
                                              float* __restrict__ H) {
  __shared__ float xs[64][K + 8];
  const int m0 = blockIdx.x * 64;
  for (int i = threadIdx.x; i < 64 * (K / 4); i += 256) {
    int m = i / (K / 4), q = i % (K / 4);
    float4 v = *reinterpret_cast<const float4*>(X + (size_t)(m0 + m) * K + q * 4);
    *reinterpret_cast<float4*>(&xs[m][q * 4]) = v;
  }
  __syncthreads();
  const int c = threadIdx.x & 63;
  const int mg = (threadIdx.x >> 6) * 16;
  float acc[16];
#pragma unroll
  for (int i = 0; i < 16; ++i) acc[i] = 0.f;
  for (int k = 0; k < K; k += 4) {
    float w0 = W[(k + 0) * 64 + c];
    float w1 = W[(k + 1) * 64 + c];
    float w2 = W[(k + 2) * 64 + c];
    float w3 = W[(k + 3) * 64 + c];
#pragma unroll
    for (int i = 0; i < 16; ++i) {
      float4 xv = *reinterpret_cast<const float4*>(&xs[mg + i][k]);
      float a = acc[i];
      a = fmaf(xv.x, w0, a);
      a = fmaf(xv.y, w1, a);
      a = fmaf(xv.z, w2, a);
      a = fmaf(xv.w, w3, a);
      acc[i] = a;
    }
  }
#pragma unroll
  for (int i = 0; i < 16; ++i)
    H[(size_t)(m0 + mg + i) * 64 + c] = acc[i];
}

// ---------------------------------------------------------------------------
// CSR build, once per graph: csr (src*20, dst-sorted), off[401], dinv,
// perm (nodes sorted by descending degree -> balanced gather waves).
// ---------------------------------------------------------------------------
__global__ __launch_bounds__(512) void csr_build(
    const int* __restrict__ src, const int* __restrict__ dst,
    unsigned short* __restrict__ csr_g, int* __restrict__ off_g,
    float* __restrict__ dinv_g, unsigned short* __restrict__ perm_g) {
  __shared__ int            deg[NN];
  __shared__ int            off[NN + 1];
  __shared__ int            cur[NN];
  __shared__ unsigned short csr[EPG];
  __shared__ unsigned short perm[NN];
  const int g = blockIdx.x, tid = threadIdx.x;
  const int e0 = g * EPG;

  for (int i = tid; i < NN; i += 512) deg[i] = 0;
  __syncthreads();

  int epack[13];
#pragma unroll
  for (int u = 0; u < 13; ++u) {
    int e = tid + u * 512;
    int pk = -1;
    if (e < EPG) {
      int ls = src[e0 + e] - g * NN;
      int ld = dst[e0 + e] - g * NN;
      pk = ls | (ld << 16);
      atomicAdd(&deg[ld], 1);
    }
    epack[u] = pk;
  }
  __syncthreads();

  if (tid <= NN) {
    int s = 0;
    for (int j = 0; j < tid; ++j) s += deg[j];
    off[tid] = s;
    if (tid < NN) cur[tid] = s;
  }
  if (tid < NN) {
    int dg = deg[tid];
    int r = 0;
    for (int j = 0; j < NN; ++j) {
      int dj = deg[j];
      r += (dj > dg) || (dj == dg && j < tid);
    }
    perm[r] = (unsigned short)tid;
    dinv_g[g * NN + tid] = 1.0f / sqrtf((float)dg + 1.0f);
  }
  __syncthreads();

#pragma unroll
  for (int u = 0; u < 13; ++u) {
    int pk = epack[u];
    if (pk != -1) {
      int p = atomicAdd(&cur[pk >> 16], 1);
      csr[p] = (unsigned short)((pk & 0xFFFF) * 20);   // premultiplied stride
    }
  }
  __syncthreads();

  // coalesced copies to global
  unsigned int* gc = (unsigned int*)(csr_g + (size_t)g * EPG);
  const unsigned int* lc = (const unsigned int*)csr;
  for (int i = tid; i < EPG / 2; i += 512) gc[i] = lc[i];
  if (tid <= NN) off_g[g * (NN + 1) + tid] = off[tid];
  unsigned int* gp = (unsigned int*)(perm_g + (size_t)g * NN);
  const unsigned int* lp = (const unsigned int*)perm;
  for (int i = tid; i < NN / 2; i += 512) gp[i] = lp[i];
}

// ---------------------------------------------------------------------------
// Stage-1 conv: block (q,g) owns 16 channels of graph g. Prebuilt CSR.
// 4-lane group per dst node, float4 (b128) LDS gather, stride-20 rows.
//   out[n] = dinv[n]*(sum_{s in N(n)} hl[s] + hl[n]) + b   (hl = dinv*h)
// ---------------------------------------------------------------------------
__global__ __launch_bounds__(512) void gcn_conv1(
    float* __restrict__ h,
    const unsigned short* __restrict__ csr_g, const int* __restrict__ off_g,
    const float* __restrict__ dinv_g, const unsigned short* __restrict__ perm_g,
    const float* __restrict__ bias, const float* __restrict__ pw,
    float* __restrict__ score4) {
  __shared__ float          hl[NN * 20];     // 32000 B, float4-aligned rows
  __shared__ unsigned short csr[EPG];        // 12800 B
  __shared__ int            off[NN + 1];
  __shared__ float          dinv[NN];
  __shared__ unsigned short perm[NN];

  const int q = blockIdx.x, g = blockIdx.y;
  const int tid = threadIdx.x;
  const size_t hbase = (size_t)g * NN * 64 + q * 16;

  // stage CSR data (coalesced u32 copies)
  {
    const unsigned int* gc = (const unsigned int*)(csr_g + (size_t)g * EPG);
    unsigned int* lc = (unsigned int*)csr;
    for (int i = tid; i < EPG / 2; i += 512) lc[i] = gc[i];
    for (int i = tid; i <= NN; i += 512) off[i] = off_g[g * (NN + 1) + i];
    for (int i = tid; i < NN; i += 512) dinv[i] = dinv_g[g * NN + i];
    const unsigned int* gp = (const unsigned int*)(perm_g + (size_t)g * NN);
    unsigned int* lpm = (unsigned int*)perm;
    for (int i = tid; i < NN / 2; i += 512) lpm[i] = gp[i];
  }
  __syncthreads();   // dinv ready for hl staging

  // stage scaled h quarter (float2 granularity)
  for (int i = tid; i < NN * 8; i += 512) {
    int n = i >> 3, c2 = (i & 7) * 2;
    float2 v = *reinterpret_cast<const float2*>(&h[hbase + (size_t)n * 64 + c2]);
    float dn = dinv[n];
    *reinterpret_cast<float2*>(&hl[n * 20 + c2]) = make_float2(dn * v.x, dn * v.y);
  }
  __syncthreads();

  // gather: 4-lane group per node, 16 nodes per wave, degree-balanced order
  const int l4 = tid & 3;
  const int c4 = l4 * 4;
  const float4 bb  = *reinterpret_cast<const float4*>(&bias[q * 16 + c4]);
  const float4 pw4 = *reinterpret_cast<const float4*>(&pw[q * 16 + c4]);
  const int grpid = tid >> 2;   // 0..127

  for (int it = 0; it < 4; ++it) {
    int pidx = it * 128 + grpid;
    if (pidx >= NN) break;       // wave-uniform (400 = 3*128 + 16)
    int n = perm[pidx];
    int e = off[n], end = off[n + 1];
    float4 acc = *reinterpret_cast<const float4*>(&hl[n * 20 + c4]);  // self
    float4 ac2 = make_float4(0.f, 0.f, 0.f, 0.f);
    for (; e + 1 < end; e += 2) {
      int s0 = csr[e], s1 = csr[e + 1];
      float4 v0 = *reinterpret_cast<const float4*>(&hl[s0 + c4]);
      float4 v1 = *reinterpret_cast<const float4*>(&hl[s1 + c4]);
      acc.x += v0.x; acc.y += v0.y; acc.z += v0.z; acc.w += v0.w;
      ac2.x += v1.x; ac2.y += v1.y; ac2.z += v1.z; ac2.w += v1.w;
    }
    if (e < end) {
      float4 v0 = *reinterpret_cast<const float4*>(&hl[csr[e] + c4]);
      acc.x += v0.x; acc.y += v0.y; acc.z += v0.z; acc.w += v0.w;
    }
    float dn = dinv[n];
    float4 o;
    o.x = fmaxf(fmaf(acc.x + ac2.x, dn, bb.x), 0.f);
    o.y = fmaxf(fmaf(acc.y + ac2.y, dn, bb.y), 0.f);
    o.z = fmaxf(fmaf(acc.z + ac2.z, dn, bb.z), 0.f);
    o.w = fmaxf(fmaf(acc.w + ac2.w, dn, bb.w), 0.f);
    *reinterpret_cast<float4*>(&h[hbase + (size_t)n * 64 + c4]) = o;
    float sd = o.x * pw4.x + o.y * pw4.y + o.z * pw4.z + o.w * pw4.w;
    sd += __shfl_xor(sd, 1);
    sd += __shfl_xor(sd, 2);
    if (l4 == 0) score4[(g * NN + n) * 4 + q] = sd;
  }
}

// ---------------------------------------------------------------------------
// TopK pooling: scores from precomputed dot partials (NS=4) or raw (NS=1).
// Exact lax.top_k semantics via stable rank. Deterministic r-sum.
// ---------------------------------------------------------------------------
template<int NPER, int KK, int NS>
__global__ __launch_bounds__(512) void topk_pool_k(
    const float* __restrict__ h, const float* __restrict__ scorein,
    const float* __restrict__ pw,
    float* __restrict__ xp, int* __restrict__ nmap, float* __restrict__ rsum) {
  __shared__ float sc[NPER];
  __shared__ int   sel[KK];
  __shared__ float rsw[8][64];
  __shared__ float nrm_s;
  const int g = blockIdx.x, tid = threadIdx.x;
  const int lane = tid & 63, wave = tid >> 6;
  const size_t base = (size_t)g * NPER * 64;

  if (wave == 0) {
    float pwl = pw[lane];
    float t = pwl * pwl;
#pragma unroll
    for (int o = 32; o; o >>= 1) t += __shfl_xor(t, o);
    if (lane == 0) nrm_s = sqrtf(t);
  }
  __syncthreads();

  if (tid < NPER) {
    const float* sp = scorein + (size_t)(g * NPER + tid) * NS;
    float s = 0.f;
#pragma unroll
    for (int u = 0; u < NS; ++u) s += sp[u];
    sc[tid] = tanhf(s / nrm_s);
  }
  __syncthreads();

  if (tid < NPER) {
    float si = sc[tid];
    int r = 0;
    for (int j = 0; j < NPER; ++j) {
      float sj = sc[j];
      r += (sj > si) || (sj == si && j < tid);
    }
    nmap[g * NPER + tid] = (r < KK) ? (g * KK + r) : -1;
    if (r < KK) sel[r] = tid;
  }
  __syncthreads();

  float part = 0.f;
  for (int r = wave; r < KK; r += 8) {
    int i = sel[r];
    float s = sc[i];
    float v = h[base + (size_t)i * 64 + lane] * s;
    xp[((size_t)g * KK + r) * 64 + lane] = v;
    part += v;
  }
  rsw[wave][lane] = part;
  __syncthreads();
  if (tid < 64) {
    float r0 = ((rsw[0][tid] + rsw[1][tid]) + (rsw[2][tid] + rsw[3][tid]))
             + ((rsw[4][tid] + rsw[5][tid]) + (rsw[6][tid] + rsw[7][tid]));
    rsum[g * 64 + tid] = r0;
  }
}

// ---------------------------------------------------------------------------
// Stage-2: fused gemm (hp@W2) + conv + score dot. One block per graph.
// ---------------------------------------------------------------------------
__global__ __launch_bounds__(512) void gcn_conv2(
    const float* __restrict__ hp, float* __restrict__ h2,
    const int* __restrict__ src, const int* __restrict__ dst,
    const int* __restrict__ nmap1,
    const float* __restrict__ W, const float* __restrict__ bias,
    const float* __restrict__ pw, float* __restrict__ scraw) {
  __shared__ float          Ws[64 * 64];
  __shared__ float          hl[100 * 64];
  __shared__ unsigned char  csr[EPG];
  __shared__ int            deg[100];
  __shared__ float          dinv[100];
  __shared__ int            off[100];
  const int g = blockIdx.x, tid = threadIdx.x;
  const int lane = tid & 63, wave = tid >> 6;
  const int e0 = g * EPG, n0 = g * 100;

  for (int i = tid; i < 4096; i += 512) Ws[i] = W[i];
  if (tid < 100) deg[tid] = 0;
  __syncthreads();

  int epack[13];
#pragma unroll
  for (int u = 0; u < 13; ++u) {
    int e = tid + u * 512;
    int pk = -1;
    if (e < EPG) {
      int ns = nmap1[src[e0 + e]], nd = nmap1[dst[e0 + e]];
      if ((ns | nd) >= 0) {
        int ls = ns - n0, ld = nd - n0;
        pk = ls | (ld << 16);
        atomicAdd(&deg[ld], 1);
      }
    }
    epack[u] = pk;
  }
  __syncthreads();

  if (tid < 100) {
    dinv[tid] = 1.0f / sqrtf((float)deg[tid] + 1.0f);
    int s = 0;
    for (int j = 0; j < tid; ++j) s += deg[j];
    off[tid] = s;
  }
  __syncthreads();

  for (int n = wave; n < 100; n += 16) {
    int n2 = n + 8;
    float rv  = hp[(size_t)(n0 + n) * 64 + lane];
    float rv2 = (n2 < 100) ? hp[(size_t)(n0 + n2) * 64 + lane] : 0.f;
    float a = 0.f, a2 = 0.f;
#pragma unroll
    for (int k = 0; k < 64; ++k) {
      float w = Ws[k * 64 + lane];
      a  = fmaf(__shfl(rv,  k), w, a);
      a2 = fmaf(__shfl(rv2, k), w, a2);
    }
    hl[n * 64 + lane] = dinv[n] * a;
    if (n2 < 100) hl[n2 * 64 + lane] = dinv[n2] * a2;
  }
#pragma unroll
  for (int u = 0; u < 13; ++u) {
    int pk = epack[u];
    if (pk != -1) {
      int p = atomicAdd(&off[pk >> 16], 1);
      csr[p] = (unsigned char)(pk & 0xFFFF);
    }
  }
  __syncthreads();

  const float bcol = bias[lane], pwc = pw[lane];
  for (int n = wave; n < 100; n += 8) {
    int end = off[n], e = end - deg[n];
    float a0 = hl[n * 64 + lane], a1 = 0.f;
    for (; e + 1 < end; e += 2) {
      a0 += hl[csr[e] * 64 + lane];
      a1 += hl[csr[e + 1] * 64 + lane];
    }
    if (e < end) a0 += hl[csr[e] * 64 + lane];
    float o = fmaxf(fmaf(a0 + a1, dinv[n], bcol), 0.f);
    h2[(size_t)(n0 + n) * 64 + lane] = o;
    float sd = o * pwc;
#pragma unroll
    for (int o2 = 32; o2; o2 >>= 1) sd += __shfl_xor(sd, o2);
    if (lane == 0) scraw[n0 + n] = sd;
  }
}

// ---------------------------------------------------------------------------
// Stage-3: fused gemm (hp@W3) + conv + r3 column-sum + final linear.
// ---------------------------------------------------------------------------
__global__ __launch_bounds__(512) void gcn_conv3_final(
    const float* __restrict__ hp,
    const int* __restrict__ src, const int* __restrict__ dst,
    const int* __restrict__ nmap1, const int* __restrict__ nmap2,
    const float* __restrict__ W, const float* __restrict__ bias,
    const float* __restrict__ r1, const float* __restrict__ r2,
    const float* __restrict__ Wl, const float* __restrict__ bl,
    float* __restrict__ out) {
  __shared__ float          Ws[64 * 64];
  __shared__ float          hl[25 * 64];
  __shared__ unsigned char  csr[EPG];
  __shared__ int            deg[25];
  __shared__ float          dinv[25];
  __shared__ int            off[25];
  __shared__ float          rsw[8][64];
  const int g = blockIdx.x, tid = threadIdx.x;
  const int lane = tid & 63, wave = tid >> 6;
  const int e0 = g * EPG, n0 = g * 25;

  for (int i = tid; i < 4096; i += 512) Ws[i] = W[i];
  if (tid < 25) deg[tid] = 0;
  __syncthreads();

  int epack[13];
#pragma unroll
  for (int u = 0; u < 13; ++u) {
    int e = tid + u * 512;
    int pk = -1;
    if (e < EPG) {
      int ns = nmap1[src[e0 + e]], nd = nmap1[dst[e0 + e]];
      if ((ns | nd) >= 0) {
        int ns2 = nmap2[ns], nd2 = nmap2[nd];
        if ((ns2 | nd2) >= 0) {
          int ls = ns2 - n0, ld = nd2 - n0;
          pk = ls | (ld << 16);
          atomicAdd(&deg[ld], 1);
        }
      }
    }
    epack[u] = pk;
  }
  __syncthreads();

  if (tid < 25) {
    dinv[tid] = 1.0f / sqrtf((float)deg[tid] + 1.0f);
    int s = 0;
    for (int j = 0; j < tid; ++j) s += deg[j];
    off[tid] = s;
  }
  __syncthreads();

  for (int n = wave; n < 25; n += 16) {
    int n2 = n + 8;
    float rv  = hp[(size_t)(n0 + n) * 64 + lane];
    float rv2 = (n2 < 25) ? hp[(size_t)(n0 + n2) * 64 + lane] : 0.f;
    float a = 0.f, a2 = 0.f;
#pragma unroll
    for (int k = 0; k < 64; ++k) {
      float w = Ws[k * 64 + lane];
      a  = fmaf(__shfl(rv,  k), w, a);
      a2 = fmaf(__shfl(rv2, k), w, a2);
    }
    hl[n * 64 + lane] = dinv[n] * a;
    if (n2 < 25) hl[n2 * 64 + lane] = dinv[n2] * a2;
  }
#pragma unroll
  for (int u = 0; u < 13; ++u) {
    int pk = epack[u];
    if (pk != -1) {
      int p = atomicAdd(&off[pk >> 16], 1);
      csr[p] = (unsigned char)(pk & 0xFFFF);
    }
  }
  __syncthreads();

  const float bcol = bias[lane];
  float part = 0.f;
  for (int n = wave; n < 25; n += 8) {
    int end = off[n], e = end - deg[n];
    float a0 = hl[n * 64 + lane], a1 = 0.f;
    for (; e + 1 < end; e += 2) {
      a0 += hl[csr[e] * 64 + lane];
      a1 += hl[csr[e + 1] * 64 + lane];
    }
    if (e < end) a0 += hl[csr[e] * 64 + lane];
    part += fmaxf(fmaf(a0 + a1, dinv[n], bcol), 0.f);
  }
  rsw[wave][lane] = part;
  __syncthreads();

  if (tid < 64) {
    float r3c = ((rsw[0][tid] + rsw[1][tid]) + (rsw[2][tid] + rsw[3][tid]))
              + ((rsw[4][tid] + rsw[5][tid]) + (rsw[6][tid] + rsw[7][tid]));
    float f1 = r2[g * 64 + tid];
    float f2 = r1[g * 64 + tid];
    float p0 = r3c * Wl[tid * 2 + 0] + f1 * Wl[(64 + tid) * 2 + 0] + f2 * Wl[(128 + tid) * 2 + 0];
    float p1 = r3c * Wl[tid * 2 + 1] + f1 * Wl[(64 + tid) * 2 + 1] + f2 * Wl[(128 + tid) * 2 + 1];
#pragma unroll
    for (int o = 32; o; o >>= 1) {
      p0 += __shfl_xor(p0, o);
      p1 += __shfl_xor(p1, o);
    }
    if (tid == 0) {
      out[g * 2 + 0] = p0 + bl[0];
      out[g * 2 + 1] = p1 + bl[1];
    }
  }
}

// ---------------------------------------------------------------------------
extern "C" void kernel_launch(void* const* d_in, const int* in_sizes, int n_in,
                              void* d_out, int out_size, void* d_ws, size_t ws_size,
                              hipStream_t stream) {
  const float* x   = (const float*)d_in[0];
  const int*   src = (const int*)d_in[1];
  const int*   dst = (const int*)d_in[2];
  const float* W1  = (const float*)d_in[4];
  const float* b1  = (const float*)d_in[5];
  const float* W2  = (const float*)d_in[6];
  const float* b2  = (const float*)d_in[7];
  const float* W3  = (const float*)d_in[8];
  const float* b3  = (const float*)d_in[9];
  const float* pw1 = (const float*)d_in[10];
  const float* pw2 = (const float*)d_in[11];
  const float* Wl  = (const float*)d_in[12];
  const float* bl  = (const float*)d_in[13];
  float* out = (float*)d_out;

  float* ws     = (float*)d_ws;
  float* h1     = ws;                                   // 102400*64
  float* score4 = h1 + (size_t)102400 * 64;             // 102400*4
  float* hp1    = score4 + (size_t)102400 * 4;          // 25600*64
  int*   nmap1  = (int*)(hp1 + (size_t)25600 * 64);     // 102400
  int*   nmap2  = nmap1 + 102400;                       // 25600
  float* sc2    = (float*)(nmap2 + 25600);              // 25600
  float* r1     = sc2 + 25600;                          // 16384
  float* r2     = r1 + 16384;                           // 16384
  float* h2     = h1;                                   // alias (h1 dead after topk1)
  float* hp2    = h1 + (size_t)25600 * 64;              // alias

  // CSR scratch aliases hp1 (hp1 written only at topk1, after conv1)
  unsigned short* csr_g  = (unsigned short*)hp1;                          // 3,276,800 B
  int*            off_g  = (int*)((char*)hp1 + 3276800);                  //   410,624 B
  float*          dinv_g = (float*)((char*)hp1 + 3276800 + 410624);       //   409,600 B
  unsigned short* perm_g = (unsigned short*)((char*)hp1 + 3276800 + 410624 + 409600);

  // Stage 1
  gemm64<128><<<102400 / 64, 256, 0, stream>>>(x, W1, h1);
  csr_build<<<BGR, 512, 0, stream>>>(src, dst, csr_g, off_g, dinv_g, perm_g);
  gcn_conv1<<<dim3(4, BGR), 512, 0, stream>>>(h1, csr_g, off_g, dinv_g, perm_g,
                                              b1, pw1, score4);
  topk_pool_k<400, 100, 4><<<BGR, 512, 0, stream>>>(h1, score4, pw1, hp1, nmap1, r1);

  // Stage 2 (gemm fused)
  gcn_conv2<<<BGR, 512, 0, stream>>>(hp1, h2, src, dst, nmap1, W2, b2, pw2, sc2);
  topk_pool_k<100, 25, 1><<<BGR, 512, 0, stream>>>(h2, sc2, pw2, hp2, nmap2, r2);

  // Stage 3 (gemm + r3 + final linear fused)
  gcn_conv3_final<<<BGR, 512, 0, stream>>>(hp2, src, dst, nmap1, nmap2,
                                           W3, b3, r1, r2, Wl, bl, out);
}

// Round 5
// 205.253 us; speedup vs baseline: 1.0570x; 1.0570x over previous
//
#include <hip/hip_runtime.h>
#include <hip/hip_bf16.h>
#include <math.h>

#define BGR  256      // graphs
#define NN   400      // nodes per graph (stage 1)
#define EPG  6400     // edges per graph

// ---------------------------------------------------------------------------
// GEMM: H[M x 64] = X[M x K] @ W[K x 64], M multiple of 64, f32.
// ---------------------------------------------------------------------------
template<int K>
__global__ __launch_bounds__(256) void gemm64(const float* __restrict__ X,
                                              const float* __restrict__ W,
                                              float* __restrict__ H) {
  __shared__ float xs[64][K + 8];
  const int m0 = blockIdx.x * 64;
  for (int i = threadIdx.x; i < 64 * (K / 4); i += 256) {
    int m = i / (K / 4), q = i % (K / 4);
    float4 v = *reinterpret_cast<const float4*>(X + (size_t)(m0 + m) * K + q * 4);
    *reinterpret_cast<float4*>(&xs[m][q * 4]) = v;
  }
  __syncthreads();
  const int c = threadIdx.x & 63;
  const int mg = (threadIdx.x >> 6) * 16;
  float acc[16];
#pragma unroll
  for (int i = 0; i < 16; ++i) acc[i] = 0.f;
  for (int k = 0; k < K; k += 4) {
    float w0 = W[(k + 0) * 64 + c];
    float w1 = W[(k + 1) * 64 + c];
    float w2 = W[(k + 2) * 64 + c];
    float w3 = W[(k + 3) * 64 + c];
#pragma unroll
    for (int i = 0; i < 16; ++i) {
      float4 xv = *reinterpret_cast<const float4*>(&xs[mg + i][k]);
      float a = acc[i];
      a = fmaf(xv.x, w0, a);
      a = fmaf(xv.y, w1, a);
      a = fmaf(xv.z, w2, a);
      a = fmaf(xv.w, w3, a);
      acc[i] = a;
    }
  }
#pragma unroll
  for (int i = 0; i < 16; ++i)
    H[(size_t)(m0 + mg + i) * 64 + c] = acc[i];
}

// ---------------------------------------------------------------------------
// CSR build, once per graph, 1024 threads: csr (src*18, dst-sorted), off[401],
// dinv, perm (nodes by descending degree -> balanced gather groups).
// ---------------------------------------------------------------------------
__global__ __launch_bounds__(1024) void csr_build(
    const int* __restrict__ src, const int* __restrict__ dst,
    unsigned short* __restrict__ csr_g, int* __restrict__ off_g,
    float* __restrict__ dinv_g, unsigned short* __restrict__ perm_g) {
  __shared__ int            deg[NN];
  __shared__ int            off[NN + 1];
  __shared__ int            cur[NN];
  __shared__ unsigned short csr[EPG];
  __shared__ unsigned short perm[NN];
  const int g = blockIdx.x, tid = threadIdx.x;
  const int e0 = g * EPG;

  for (int i = tid; i < NN; i += 1024) deg[i] = 0;
  __syncthreads();

  int epack[7];
#pragma unroll
  for (int u = 0; u < 7; ++u) {
    int e = tid + u * 1024;
    int pk = -1;
    if (e < EPG) {
      int ls = src[e0 + e] - g * NN;
      int ld = dst[e0 + e] - g * NN;
      pk = ls | (ld << 16);
      atomicAdd(&deg[ld], 1);
    }
    epack[u] = pk;
  }
  __syncthreads();

  if (tid <= NN) {
    int s = 0;
    for (int j = 0; j < tid; ++j) s += deg[j];
    off[tid] = s;
    if (tid < NN) cur[tid] = s;
  }
  if (tid < NN) {
    int dg = deg[tid];
    int r = 0;
    for (int j = 0; j < NN; ++j) {
      int dj = deg[j];
      r += (dj > dg) || (dj == dg && j < tid);
    }
    perm[r] = (unsigned short)tid;
    dinv_g[g * NN + tid] = 1.0f / sqrtf((float)dg + 1.0f);
  }
  __syncthreads();

#pragma unroll
  for (int u = 0; u < 7; ++u) {
    int pk = epack[u];
    if (pk != -1) {
      int p = atomicAdd(&cur[pk >> 16], 1);
      csr[p] = (unsigned short)((pk & 0xFFFF) * 18);   // premult by row stride
    }
  }
  __syncthreads();

  unsigned int* gc = (unsigned int*)(csr_g + (size_t)g * EPG);
  const unsigned int* lc = (const unsigned int*)csr;
  for (int i = tid; i < EPG / 2; i += 1024) gc[i] = lc[i];
  if (tid <= NN) off_g[g * (NN + 1) + tid] = off[tid];
  unsigned int* gp = (unsigned int*)(perm_g + (size_t)g * NN);
  const unsigned int* lp = (const unsigned int*)perm;
  for (int i = tid; i < NN / 2; i += 1024) gp[i] = lp[i];
}

// ---------------------------------------------------------------------------
// Stage-1 conv: block (q,g) owns 16 channels of graph g. Prebuilt CSR.
// 8-lane group per dst node, float2 (b64) LDS gather, stride-18 rows
// (even start bank, ~2-way aliasing = free). CSR entries via uniform u32
// broadcast reads.  out[n] = dinv[n]*(sum_s hl[s] + hl[n]) + b, hl = dinv*h.
// ---------------------------------------------------------------------------
__global__ __launch_bounds__(512) void gcn_conv1(
    float* __restrict__ h,
    const unsigned short* __restrict__ csr_g, const int* __restrict__ off_g,
    const float* __restrict__ dinv_g, const unsigned short* __restrict__ perm_g,
    const float* __restrict__ bias, const float* __restrict__ pw,
    float* __restrict__ score4) {
  __shared__ float          hl[NN * 18];     // 28800 B
  __shared__ unsigned short csr[EPG];        // 12800 B
  __shared__ int            off[NN + 1];
  __shared__ float          dinv[NN];
  __shared__ unsigned short perm[NN];

  const int q = blockIdx.x, g = blockIdx.y;
  const int tid = threadIdx.x;
  const size_t hbase = (size_t)g * NN * 64 + q * 16;

  // stage CSR data (coalesced u32 copies)
  {
    const unsigned int* gc = (const unsigned int*)(csr_g + (size_t)g * EPG);
    unsigned int* lc = (unsigned int*)csr;
    for (int i = tid; i < EPG / 2; i += 512) lc[i] = gc[i];
    for (int i = tid; i <= NN; i += 512) off[i] = off_g[g * (NN + 1) + i];
    for (int i = tid; i < NN; i += 512) dinv[i] = dinv_g[g * NN + i];
    const unsigned int* gp = (const unsigned int*)(perm_g + (size_t)g * NN);
    unsigned int* lpm = (unsigned int*)perm;
    for (int i = tid; i < NN / 2; i += 512) lpm[i] = gp[i];
  }
  __syncthreads();

  // stage scaled h quarter (float2 per lane)
  for (int i = tid; i < NN * 8; i += 512) {
    int n = i >> 3, c2 = (i & 7) * 2;
    float2 v = *reinterpret_cast<const float2*>(&h[hbase + (size_t)n * 64 + c2]);
    float dn = dinv[n];
    *reinterpret_cast<float2*>(&hl[n * 18 + c2]) = make_float2(dn * v.x, dn * v.y);
  }
  __syncthreads();

  // gather: 8-lane group per node, degree-balanced order
  const int l8 = tid & 7;
  const int c2 = l8 * 2;
  const int grpid = tid >> 3;               // 0..63
  const float2 bb  = *reinterpret_cast<const float2*>(&bias[q * 16 + c2]);
  const float2 pv2 = *reinterpret_cast<const float2*>(&pw[q * 16 + c2]);

  for (int pidx = grpid; pidx < NN; pidx += 64) {
    int n = perm[pidx];
    int e = off[n], end = off[n + 1];
    float ax = hl[n * 18 + c2], ay = hl[n * 18 + c2 + 1];   // self term
    float bx = 0.f, by = 0.f, cx = 0.f, cy = 0.f, dx = 0.f, dy = 0.f;
    if (e < end && (e & 1)) {              // peel to even
      int s = csr[e];
      ax += hl[s + c2]; ay += hl[s + c2 + 1];
      ++e;
    }
    while (e + 4 <= end) {
      unsigned p0 = *reinterpret_cast<const unsigned*>(&csr[e]);
      unsigned p1 = *reinterpret_cast<const unsigned*>(&csr[e + 2]);
      int s0 = p0 & 0xFFFF, s1 = p0 >> 16;
      int s2 = p1 & 0xFFFF, s3 = p1 >> 16;
      ax += hl[s0 + c2]; ay += hl[s0 + c2 + 1];
      bx += hl[s1 + c2]; by += hl[s1 + c2 + 1];
      cx += hl[s2 + c2]; cy += hl[s2 + c2 + 1];
      dx += hl[s3 + c2]; dy += hl[s3 + c2 + 1];
      e += 4;
    }
    if (e + 2 <= end) {
      unsigned p0 = *reinterpret_cast<const unsigned*>(&csr[e]);
      int s0 = p0 & 0xFFFF, s1 = p0 >> 16;
      ax += hl[s0 + c2]; ay += hl[s0 + c2 + 1];
      bx += hl[s1 + c2]; by += hl[s1 + c2 + 1];
      e += 2;
    }
    if (e < end) {
      int s = csr[e];
      cx += hl[s + c2]; cy += hl[s + c2 + 1];
    }
    float dn = dinv[n];
    float ox = fmaxf(fmaf((ax + bx) + (cx + dx), dn, bb.x), 0.f);
    float oy = fmaxf(fmaf((ay + by) + (cy + dy), dn, bb.y), 0.f);
    *reinterpret_cast<float2*>(&h[hbase + (size_t)n * 64 + c2]) =
        make_float2(ox, oy);
    float sd = ox * pv2.x + oy * pv2.y;
    sd += __shfl_xor(sd, 1);
    sd += __shfl_xor(sd, 2);
    sd += __shfl_xor(sd, 4);
    if (l8 == 0) score4[(g * NN + n) * 4 + q] = sd;
  }
}

// ---------------------------------------------------------------------------
// TopK pooling: scores from precomputed dot partials (NS=4) or raw (NS=1).
// Exact lax.top_k semantics via stable rank. Deterministic r-sum.
// ---------------------------------------------------------------------------
template<int NPER, int KK, int NS>
__global__ __launch_bounds__(512) void topk_pool_k(
    const float* __restrict__ h, const float* __restrict__ scorein,
    const float* __restrict__ pw,
    float* __restrict__ xp, int* __restrict__ nmap, float* __restrict__ rsum) {
  __shared__ float sc[NPER];
  __shared__ int   sel[KK];
  __shared__ float rsw[8][64];
  __shared__ float nrm_s;
  const int g = blockIdx.x, tid = threadIdx.x;
  const int lane = tid & 63, wave = tid >> 6;
  const size_t base = (size_t)g * NPER * 64;

  if (wave == 0) {
    float pwl = pw[lane];
    float t = pwl * pwl;
#pragma unroll
    for (int o = 32; o; o >>= 1) t += __shfl_xor(t, o);
    if (lane == 0) nrm_s = sqrtf(t);
  }
  __syncthreads();

  if (tid < NPER) {
    const float* sp = scorein + (size_t)(g * NPER + tid) * NS;
    float s = 0.f;
#pragma unroll
    for (int u = 0; u < NS; ++u) s += sp[u];
    sc[tid] = tanhf(s / nrm_s);
  }
  __syncthreads();

  if (tid < NPER) {
    float si = sc[tid];
    int r = 0;
    for (int j = 0; j < NPER; ++j) {
      float sj = sc[j];
      r += (sj > si) || (sj == si && j < tid);
    }
    nmap[g * NPER + tid] = (r < KK) ? (g * KK + r) : -1;
    if (r < KK) sel[r] = tid;
  }
  __syncthreads();

  float part = 0.f;
  for (int r = wave; r < KK; r += 8) {
    int i = sel[r];
    float s = sc[i];
    float v = h[base + (size_t)i * 64 + lane] * s;
    xp[((size_t)g * KK + r) * 64 + lane] = v;
    part += v;
  }
  rsw[wave][lane] = part;
  __syncthreads();
  if (tid < 64) {
    float r0 = ((rsw[0][tid] + rsw[1][tid]) + (rsw[2][tid] + rsw[3][tid]))
             + ((rsw[4][tid] + rsw[5][tid]) + (rsw[6][tid] + rsw[7][tid]));
    rsum[g * 64 + tid] = r0;
  }
}

// ---------------------------------------------------------------------------
// Stage-2: fused gemm (hp@W2) + conv + score dot. One block per graph.
// ---------------------------------------------------------------------------
__global__ __launch_bounds__(512) void gcn_conv2(
    const float* __restrict__ hp, float* __restrict__ h2,
    const int* __restrict__ src, const int* __restrict__ dst,
    const int* __restrict__ nmap1,
    const float* __restrict__ W, const float* __restrict__ bias,
    const float* __restrict__ pw, float* __restrict__ scraw) {
  __shared__ float          Ws[64 * 64];
  __shared__ float          hl[100 * 64];
  __shared__ unsigned char  csr[EPG];
  __shared__ int            deg[100];
  __shared__ float          dinv[100];
  __shared__ int            off[100];
  const int g = blockIdx.x, tid = threadIdx.x;
  const int lane = tid & 63, wave = tid >> 6;
  const int e0 = g * EPG, n0 = g * 100;

  for (int i = tid; i < 4096; i += 512) Ws[i] = W[i];
  if (tid < 100) deg[tid] = 0;
  __syncthreads();

  int epack[13];
#pragma unroll
  for (int u = 0; u < 13; ++u) {
    int e = tid + u * 512;
    int pk = -1;
    if (e < EPG) {
      int ns = nmap1[src[e0 + e]], nd = nmap1[dst[e0 + e]];
      if ((ns | nd) >= 0) {
        int ls = ns - n0, ld = nd - n0;
        pk = ls | (ld << 16);
        atomicAdd(&deg[ld], 1);
      }
    }
    epack[u] = pk;
  }
  __syncthreads();

  if (tid < 100) {
    dinv[tid] = 1.0f / sqrtf((float)deg[tid] + 1.0f);
    int s = 0;
    for (int j = 0; j < tid; ++j) s += deg[j];
    off[tid] = s;
  }
  __syncthreads();

  for (int n = wave; n < 100; n += 16) {
    int n2 = n + 8;
    float rv  = hp[(size_t)(n0 + n) * 64 + lane];
    float rv2 = (n2 < 100) ? hp[(size_t)(n0 + n2) * 64 + lane] : 0.f;
    float a = 0.f, a2 = 0.f;
#pragma unroll
    for (int k = 0; k < 64; ++k) {
      float w = Ws[k * 64 + lane];
      a  = fmaf(__shfl(rv,  k), w, a);
      a2 = fmaf(__shfl(rv2, k), w, a2);
    }
    hl[n * 64 + lane] = dinv[n] * a;
    if (n2 < 100) hl[n2 * 64 + lane] = dinv[n2] * a2;
  }
#pragma unroll
  for (int u = 0; u < 13; ++u) {
    int pk = epack[u];
    if (pk != -1) {
      int p = atomicAdd(&off[pk >> 16], 1);
      csr[p] = (unsigned char)(pk & 0xFFFF);
    }
  }
  __syncthreads();

  const float bcol = bias[lane], pwc = pw[lane];
  for (int n = wave; n < 100; n += 8) {
    int end = off[n], e = end - deg[n];
    float a0 = hl[n * 64 + lane], a1 = 0.f;
    for (; e + 1 < end; e += 2) {
      a0 += hl[csr[e] * 64 + lane];
      a1 += hl[csr[e + 1] * 64 + lane];
    }
    if (e < end) a0 += hl[csr[e] * 64 + lane];
    float o = fmaxf(fmaf(a0 + a1, dinv[n], bcol), 0.f);
    h2[(size_t)(n0 + n) * 64 + lane] = o;
    float sd = o * pwc;
#pragma unroll
    for (int o2 = 32; o2; o2 >>= 1) sd += __shfl_xor(sd, o2);
    if (lane == 0) scraw[n0 + n] = sd;
  }
}

// ---------------------------------------------------------------------------
// Stage-3: fused gemm (hp@W3) + conv + r3 column-sum + final linear.
// ---------------------------------------------------------------------------
__global__ __launch_bounds__(512) void gcn_conv3_final(
    const float* __restrict__ hp,
    const int* __restrict__ src, const int* __restrict__ dst,
    const int* __restrict__ nmap1, const int* __restrict__ nmap2,
    const float* __restrict__ W, const float* __restrict__ bias,
    const float* __restrict__ r1, const float* __restrict__ r2,
    const float* __restrict__ Wl, const float* __restrict__ bl,
    float* __restrict__ out) {
  __shared__ float          Ws[64 * 64];
  __shared__ float          hl[25 * 64];
  __shared__ unsigned char  csr[EPG];
  __shared__ int            deg[25];
  __shared__ float          dinv[25];
  __shared__ int            off[25];
  __shared__ float          rsw[8][64];
  const int g = blockIdx.x, tid = threadIdx.x;
  const int lane = tid & 63, wave = tid >> 6;
  const int e0 = g * EPG, n0 = g * 25;

  for (int i = tid; i < 4096; i += 512) Ws[i] = W[i];
  if (tid < 25) deg[tid] = 0;
  __syncthreads();

  int epack[13];
#pragma unroll
  for (int u = 0; u < 13; ++u) {
    int e = tid + u * 512;
    int pk = -1;
    if (e < EPG) {
      int ns = nmap1[src[e0 + e]], nd = nmap1[dst[e0 + e]];
      if ((ns | nd) >= 0) {
        int ns2 = nmap2[ns], nd2 = nmap2[nd];
        if ((ns2 | nd2) >= 0) {
          int ls = ns2 - n0, ld = nd2 - n0;
          pk = ls | (ld << 16);
          atomicAdd(&deg[ld], 1);
        }
      }
    }
    epack[u] = pk;
  }
  __syncthreads();

  if (tid < 25) {
    dinv[tid] = 1.0f / sqrtf((float)deg[tid] + 1.0f);
    int s = 0;
    for (int j = 0; j < tid; ++j) s += deg[j];
    off[tid] = s;
  }
  __syncthreads();

  for (int n = wave; n < 25; n += 16) {
    int n2 = n + 8;
    float rv  = hp[(size_t)(n0 + n) * 64 + lane];
    float rv2 = (n2 < 25) ? hp[(size_t)(n0 + n2) * 64 + lane] : 0.f;
    float a = 0.f, a2 = 0.f;
#pragma unroll
    for (int k = 0; k < 64; ++k) {
      float w = Ws[k * 64 + lane];
      a  = fmaf(__shfl(rv,  k), w, a);
      a2 = fmaf(__shfl(rv2, k), w, a2);
    }
    hl[n * 64 + lane] = dinv[n] * a;
    if (n2 < 25) hl[n2 * 64 + lane] = dinv[n2] * a2;
  }
#pragma unroll
  for (int u = 0; u < 13; ++u) {
    int pk = epack[u];
    if (pk != -1) {
      int p = atomicAdd(&off[pk >> 16], 1);
      csr[p] = (unsigned char)(pk & 0xFFFF);
    }
  }
  __syncthreads();

  const float bcol = bias[lane];
  float part = 0.f;
  for (int n = wave; n < 25; n += 8) {
    int end = off[n], e = end - deg[n];
    float a0 = hl[n * 64 + lane], a1 = 0.f;
    for (; e + 1 < end; e += 2) {
      a0 += hl[csr[e] * 64 + lane];
      a1 += hl[csr[e + 1] * 64 + lane];
    }
    if (e < end) a0 += hl[csr[e] * 64 + lane];
    part += fmaxf(fmaf(a0 + a1, dinv[n], bcol), 0.f);
  }
  rsw[wave][lane] = part;
  __syncthreads();

  if (tid < 64) {
    float r3c = ((rsw[0][tid] + rsw[1][tid]) + (rsw[2][tid] + rsw[3][tid]))
              + ((rsw[4][tid] + rsw[5][tid]) + (rsw[6][tid] + rsw[7][tid]));
    float f1 = r2[g * 64 + tid];
    float f2 = r1[g * 64 + tid];
    float p0 = r3c * Wl[tid * 2 + 0] + f1 * Wl[(64 + tid) * 2 + 0] + f2 * Wl[(128 + tid) * 2 + 0];
    float p1 = r3c * Wl[tid * 2 + 1] + f1 * Wl[(64 + tid) * 2 + 1] + f2 * Wl[(128 + tid) * 2 + 1];
#pragma unroll
    for (int o = 32; o; o >>= 1) {
      p0 += __shfl_xor(p0, o);
      p1 += __shfl_xor(p1, o);
    }
    if (tid == 0) {
      out[g * 2 + 0] = p0 + bl[0];
      out[g * 2 + 1] = p1 + bl[1];
    }
  }
}

// ---------------------------------------------------------------------------
extern "C" void kernel_launch(void* const* d_in, const int* in_sizes, int n_in,
                              void* d_out, int out_size, void* d_ws, size_t ws_size,
                              hipStream_t stream) {
  const float* x   = (const float*)d_in[0];
  const int*   src = (const int*)d_in[1];
  const int*   dst = (const int*)d_in[2];
  const float* W1  = (const float*)d_in[4];
  const float* b1  = (const float*)d_in[5];
  const float* W2  = (const float*)d_in[6];
  const float* b2  = (const float*)d_in[7];
  const float* W3  = (const float*)d_in[8];
  const float* b3  = (const float*)d_in[9];
  const float* pw1 = (const float*)d_in[10];
  const float* pw2 = (const float*)d_in[11];
  const float* Wl  = (const float*)d_in[12];
  const float* bl  = (const float*)d_in[13];
  float* out = (float*)d_out;

  float* ws     = (float*)d_ws;
  float* h1     = ws;                                   // 102400*64
  float* score4 = h1 + (size_t)102400 * 64;             // 102400*4
  float* hp1    = score4 + (size_t)102400 * 4;          // 25600*64
  int*   nmap1  = (int*)(hp1 + (size_t)25600 * 64);     // 102400
  int*   nmap2  = nmap1 + 102400;                       // 25600
  float* sc2    = (float*)(nmap2 + 25600);              // 25600
  float* r1     = sc2 + 25600;                          // 16384
  float* r2     = r1 + 16384;                           // 16384
  float* h2     = h1;                                   // alias (h1 dead after topk1)
  float* hp2    = h1 + (size_t)25600 * 64;              // alias

  // CSR scratch aliases hp1 (hp1 written only at topk1, after conv1 reads CSR)
  unsigned short* csr_g  = (unsigned short*)hp1;                          // 3,276,800 B
  int*            off_g  = (int*)((char*)hp1 + 3276800);                  //   410,624 B
  float*          dinv_g = (float*)((char*)hp1 + 3276800 + 410624);       //   409,600 B
  unsigned short* perm_g = (unsigned short*)((char*)hp1 + 3276800 + 410624 + 409600);

  // Stage 1
  gemm64<128><<<102400 / 64, 256, 0, stream>>>(x, W1, h1);
  csr_build<<<BGR, 1024, 0, stream>>>(src, dst, csr_g, off_g, dinv_g, perm_g);
  gcn_conv1<<<dim3(4, BGR), 512, 0, stream>>>(h1, csr_g, off_g, dinv_g, perm_g,
                                              b1, pw1, score4);
  topk_pool_k<400, 100, 4><<<BGR, 512, 0, stream>>>(h1, score4, pw1, hp1, nmap1, r1);

  // Stage 2 (gemm fused)
  gcn_conv2<<<BGR, 512, 0, stream>>>(hp1, h2, src, dst, nmap1, W2, b2, pw2, sc2);
  topk_pool_k<100, 25, 1><<<BGR, 512, 0, stream>>>(h2, sc2, pw2, hp2, nmap2, r2);

  // Stage 3 (gemm + r3 + final linear fused)
  gcn_conv3_final<<<BGR, 512, 0, stream>>>(hp2, src, dst, nmap1, nmap2,
                                           W3, b3, r1, r2, Wl, bl, out);
}

// Round 6
// 167.962 us; speedup vs baseline: 1.2917x; 1.2220x over previous
//
#include <hip/hip_runtime.h>
#include <hip/hip_bf16.h>
#include <math.h>

#define BGR  256      // graphs
#define NN   400      // nodes per graph (stage 1)
#define EPG  6400     // edges per graph

// ---------------------------------------------------------------------------
// GEMM: H[M x 64] = X[M x K] @ W[K x 64], M multiple of 64, f32.
// ---------------------------------------------------------------------------
template<int K>
__global__ __launch_bounds__(256) void gemm64(const float* __restrict__ X,
                                              const float* __restrict__ W,
                                              float* __restrict__ H) {
  __shared__ float xs[64][K + 8];
  const int m0 = blockIdx.x * 64;
  for (int i = threadIdx.x; i < 64 * (K / 4); i += 256) {
    int m = i / (K / 4), q = i % (K / 4);
    float4 v = *reinterpret_cast<const float4*>(X + (size_t)(m0 + m) * K + q * 4);
    *reinterpret_cast<float4*>(&xs[m][q * 4]) = v;
  }
  __syncthreads();
  const int c = threadIdx.x & 63;
  const int mg = (threadIdx.x >> 6) * 16;
  float acc[16];
#pragma unroll
  for (int i = 0; i < 16; ++i) acc[i] = 0.f;
  for (int k = 0; k < K; k += 4) {
    float w0 = W[(k + 0) * 64 + c];
    float w1 = W[(k + 1) * 64 + c];
    float w2 = W[(k + 2) * 64 + c];
    float w3 = W[(k + 3) * 64 + c];
#pragma unroll
    for (int i = 0; i < 16; ++i) {
      float4 xv = *reinterpret_cast<const float4*>(&xs[mg + i][k]);
      float a = acc[i];
      a = fmaf(xv.x, w0, a);
      a = fmaf(xv.y, w1, a);
      a = fmaf(xv.z, w2, a);
      a = fmaf(xv.w, w3, a);
      acc[i] = a;
    }
  }
#pragma unroll
  for (int i = 0; i < 16; ++i)
    H[(size_t)(m0 + mg + i) * 64 + c] = acc[i];
}

// ---------------------------------------------------------------------------
// Stage 1 mega-kernel, one block per graph (1024 threads):
// CSR build (parallel scan) + conv (LDS gather, channel-complete 256B rows =
// bank-uniform) + topk select + hp1 / nmap1 / r1 output. h1-post never
// touches HBM.
// ---------------------------------------------------------------------------
__global__ __launch_bounds__(1024) void fused_stage1(
    const float* __restrict__ h1,
    const int* __restrict__ src, const int* __restrict__ dst,
    const float* __restrict__ bias, const float* __restrict__ pw,
    float* __restrict__ hp1, int* __restrict__ nmap, float* __restrict__ rsum) {
  __shared__ float          hl[NN * 64];      // 102400 B
  __shared__ unsigned short csr[EPG];         // 12800 B (src local id * 64)
  __shared__ int            off[NN + 1];
  __shared__ int            cur[NN];
  __shared__ int            deg[NN];
  __shared__ float          dinv[NN];
  __shared__ float          sc[NN];
  __shared__ int            sel[100];
  __shared__ float          red[64][64];      // 16384 B (r1 reduce)
  __shared__ int            wpart[8];
  __shared__ float          nrm_s;

  const int g = blockIdx.x;
  const int tid = threadIdx.x;
  const int e0 = g * EPG;
  const size_t hbase = (size_t)g * NN * 64;

  for (int i = tid; i < NN; i += 1024) deg[i] = 0;
  if (tid < 64) {                              // wave 0: ||pw||
    float p = pw[tid];
    float t = p * p;
#pragma unroll
    for (int o = 32; o; o >>= 1) t += __shfl_xor(t, o);
    if (tid == 0) nrm_s = sqrtf(t);
  }
  __syncthreads();

  // ---- edge pass: pack (ls,ld) in regs, count degree ----
  int epack[7];
#pragma unroll
  for (int u = 0; u < 7; ++u) {
    int e = tid + u * 1024;
    int pk = -1;
    if (e < EPG) {
      int ls = src[e0 + e] - g * NN;
      int ld = dst[e0 + e] - g * NN;
      pk = ls | (ld << 16);
      atomicAdd(&deg[ld], 1);
    }
    epack[u] = pk;
  }
  __syncthreads();

  // ---- parallel exclusive scan of deg -> off/cur; dinv ----
  int myincl = 0, myd = 0;
  if (tid < NN) {
    myd = deg[tid];
    int v = myd;
#pragma unroll
    for (int o = 1; o < 64; o <<= 1) {
      int t = __shfl_up(v, o);
      if ((tid & 63) >= o) v += t;
    }
    myincl = v;
    dinv[tid] = 1.0f / sqrtf((float)myd + 1.0f);
    if ((tid & 63) == 63 || tid == NN - 1) wpart[tid >> 6] = v;
  }
  __syncthreads();
  if (tid < NN) {
    int base = 0;
    int w = tid >> 6;
    for (int j = 0; j < w; ++j) base += wpart[j];
    int incl = base + myincl;
    off[tid + 1] = incl;
    cur[tid] = incl - myd;
    if (tid == 0) off[0] = 0;
  }
  __syncthreads();

  // ---- stage scaled h (full 64 ch) + fill CSR ----
  for (int i = tid; i < NN * 16; i += 1024) {
    int n = i >> 4, c4 = (i & 15) * 4;
    float4 v = *reinterpret_cast<const float4*>(&h1[hbase + (size_t)n * 64 + c4]);
    float dn = dinv[n];
    v.x *= dn; v.y *= dn; v.z *= dn; v.w *= dn;
    *reinterpret_cast<float4*>(&hl[n * 64 + c4]) = v;
  }
#pragma unroll
  for (int u = 0; u < 7; ++u) {
    int pk = epack[u];
    if (pk != -1) {
      int p = atomicAdd(&cur[pk >> 16], 1);
      csr[p] = (unsigned short)((pk & 0xFFFF) << 6);   // premult by 64
    }
  }
  __syncthreads();

  // ---- gather: 16-lane group per node, float4 per lane (full 256B rows) ----
  const int grp = tid >> 4, l16 = tid & 15, c4v = l16 * 4;
  const float4 bb  = *reinterpret_cast<const float4*>(&bias[c4v]);
  const float4 pw4 = *reinterpret_cast<const float4*>(&pw[c4v]);
  float4 outv[7];
  int cnt = 0;
  for (int n = grp; n < NN; n += 64, ++cnt) {
    int e = off[n], end = off[n + 1];
    float4 a = *reinterpret_cast<const float4*>(&hl[n * 64 + c4v]);  // self
    float4 b = make_float4(0.f, 0.f, 0.f, 0.f);
    if (e < end && (e & 1)) {
      int s = csr[e];
      float4 v = *reinterpret_cast<const float4*>(&hl[s + c4v]);
      a.x += v.x; a.y += v.y; a.z += v.z; a.w += v.w;
      ++e;
    }
    while (e + 4 <= end) {
      unsigned p0 = *reinterpret_cast<const unsigned*>(&csr[e]);
      unsigned p1 = *reinterpret_cast<const unsigned*>(&csr[e + 2]);
      int s0 = p0 & 0xFFFF, s1 = p0 >> 16;
      int s2 = p1 & 0xFFFF, s3 = p1 >> 16;
      float4 v0 = *reinterpret_cast<const float4*>(&hl[s0 + c4v]);
      float4 v1 = *reinterpret_cast<const float4*>(&hl[s1 + c4v]);
      float4 v2 = *reinterpret_cast<const float4*>(&hl[s2 + c4v]);
      float4 v3 = *reinterpret_cast<const float4*>(&hl[s3 + c4v]);
      a.x += v0.x; a.y += v0.y; a.z += v0.z; a.w += v0.w;
      b.x += v1.x; b.y += v1.y; b.z += v1.z; b.w += v1.w;
      a.x += v2.x; a.y += v2.y; a.z += v2.z; a.w += v2.w;
      b.x += v3.x; b.y += v3.y; b.z += v3.z; b.w += v3.w;
      e += 4;
    }
    if (e + 2 <= end) {
      unsigned p0 = *reinterpret_cast<const unsigned*>(&csr[e]);
      int s0 = p0 & 0xFFFF, s1 = p0 >> 16;
      float4 v0 = *reinterpret_cast<const float4*>(&hl[s0 + c4v]);
      float4 v1 = *reinterpret_cast<const float4*>(&hl[s1 + c4v]);
      a.x += v0.x; a.y += v0.y; a.z += v0.z; a.w += v0.w;
      b.x += v1.x; b.y += v1.y; b.z += v1.z; b.w += v1.w;
      e += 2;
    }
    if (e < end) {
      int s = csr[e];
      float4 v = *reinterpret_cast<const float4*>(&hl[s + c4v]);
      a.x += v.x; a.y += v.y; a.z += v.z; a.w += v.w;
    }
    float dn = dinv[n];
    float4 o;
    o.x = fmaxf(fmaf(a.x + b.x, dn, bb.x), 0.f);
    o.y = fmaxf(fmaf(a.y + b.y, dn, bb.y), 0.f);
    o.z = fmaxf(fmaf(a.z + b.z, dn, bb.z), 0.f);
    o.w = fmaxf(fmaf(a.w + b.w, dn, bb.w), 0.f);
    outv[cnt] = o;
    float sd = o.x * pw4.x + o.y * pw4.y + o.z * pw4.z + o.w * pw4.w;
    sd += __shfl_xor(sd, 1);
    sd += __shfl_xor(sd, 2);
    sd += __shfl_xor(sd, 4);
    sd += __shfl_xor(sd, 8);
    if (l16 == 0) sc[n] = sd;
  }
  __syncthreads();   // all reads of hl done

  // ---- write post values back into hl; tanh scores ----
  cnt = 0;
  for (int n = grp; n < NN; n += 64, ++cnt)
    *reinterpret_cast<float4*>(&hl[n * 64 + c4v]) = outv[cnt];
  if (tid < NN) sc[tid] = tanhf(sc[tid] / nrm_s);
  __syncthreads();

  // ---- stable rank top-100 ----
  if (tid < NN) {
    float si = sc[tid];
    int r = 0;
    for (int j = 0; j < NN; ++j) {
      float sj = sc[j];
      r += (sj > si) || (sj == si && j < tid);
    }
    nmap[g * NN + tid] = (r < 100) ? (g * 100 + r) : -1;
    if (r < 100) sel[r] = tid;
  }
  __syncthreads();

  // ---- hp1 write + r1 column sums (deterministic) ----
  {
    int r = tid >> 4, c4 = (tid & 15) * 4;
    int n = sel[r];
    float s = sc[n];
    float4 v = *reinterpret_cast<const float4*>(&hl[n * 64 + c4]);
    v.x *= s; v.y *= s; v.z *= s; v.w *= s;
    *reinterpret_cast<float4*>(&hp1[((size_t)g * 100 + r) * 64 + c4]) = v;
    int i2 = tid + 1024;
    if (i2 < 1600) {
      int r2 = i2 >> 4;
      int n2 = sel[r2];
      float s2 = sc[n2];
      float4 v2 = *reinterpret_cast<const float4*>(&hl[n2 * 64 + c4]);
      v2.x *= s2; v2.y *= s2; v2.z *= s2; v2.w *= s2;
      *reinterpret_cast<float4*>(&hp1[((size_t)g * 100 + r2) * 64 + c4]) = v2;
      v.x += v2.x; v.y += v2.y; v.z += v2.z; v.w += v2.w;
    }
    *reinterpret_cast<float4*>(&red[r][c4]) = v;
  }
  __syncthreads();
  if (tid < 64) {
    float s = 0.f;
    for (int rs = 0; rs < 64; ++rs) s += red[rs][tid];
    rsum[g * 64 + tid] = s;
  }
}

// ---------------------------------------------------------------------------
// Stage 2 mega-kernel: gemm (hp1@W2) + conv + topk + hp2 / nmap2 / r2.
// One block (512 thr) per graph. Ws aliases hpost (dead by gather phase).
// ---------------------------------------------------------------------------
__global__ __launch_bounds__(512) void fused_stage2(
    const float* __restrict__ hp,
    const int* __restrict__ src, const int* __restrict__ dst,
    const int* __restrict__ nmap1,
    const float* __restrict__ W, const float* __restrict__ bias,
    const float* __restrict__ pw,
    float* __restrict__ hp2, int* __restrict__ nmap2, float* __restrict__ rsum) {
  __shared__ float          hl[100 * 64];     // pre (dinv-scaled gemm out)
  __shared__ float          hpost[100 * 64];  // post; first 4096 floats = Ws
  __shared__ unsigned char  csr[EPG];
  __shared__ int            deg[100];
  __shared__ float          dinv[100];
  __shared__ int            off[101];
  __shared__ int            cur[100];
  __shared__ float          sc[100];
  __shared__ int            sel[25];
  __shared__ float          red[25][64];
  __shared__ float          nrm_s;
  float* Ws = hpost;                          // alias (16 KB)

  const int g = blockIdx.x, tid = threadIdx.x;
  const int lane = tid & 63, wave = tid >> 6;
  const int e0 = g * EPG, n0 = g * 100;

  for (int i = tid; i < 4096; i += 512) Ws[i] = W[i];
  if (tid < 100) deg[tid] = 0;
  if (wave == 7) {
    float p = pw[lane];
    float t = p * p;
#pragma unroll
    for (int o = 32; o; o >>= 1) t += __shfl_xor(t, o);
    if (lane == 0) nrm_s = sqrtf(t);
  }
  __syncthreads();

  int epack[13];
#pragma unroll
  for (int u = 0; u < 13; ++u) {
    int e = tid + u * 512;
    int pk = -1;
    if (e < EPG) {
      int ns = nmap1[src[e0 + e]], nd = nmap1[dst[e0 + e]];
      if ((ns | nd) >= 0) {
        pk = (ns - n0) | ((nd - n0) << 16);
        atomicAdd(&deg[nd - n0], 1);
      }
    }
    epack[u] = pk;
  }
  __syncthreads();

  if (tid < 100) {
    int d = deg[tid];
    dinv[tid] = 1.0f / sqrtf((float)d + 1.0f);
    int s = 0;
    for (int j = 0; j < tid; ++j) s += deg[j];
    off[tid] = s;
    cur[tid] = s;
    if (tid == 99) off[100] = s + d;
  }
  __syncthreads();

  // gemm into hl (scaled); csr fill
  for (int n = wave; n < 100; n += 16) {
    int n2 = n + 8;
    float rv  = hp[(size_t)(n0 + n) * 64 + lane];
    float rv2 = (n2 < 100) ? hp[(size_t)(n0 + n2) * 64 + lane] : 0.f;
    float a = 0.f, a2 = 0.f;
#pragma unroll
    for (int k = 0; k < 64; ++k) {
      float w = Ws[k * 64 + lane];
      a  = fmaf(__shfl(rv,  k), w, a);
      a2 = fmaf(__shfl(rv2, k), w, a2);
    }
    hl[n * 64 + lane] = dinv[n] * a;
    if (n2 < 100) hl[n2 * 64 + lane] = dinv[n2] * a2;
  }
#pragma unroll
  for (int u = 0; u < 13; ++u) {
    int pk = epack[u];
    if (pk != -1) {
      int p = atomicAdd(&cur[pk >> 16], 1);
      csr[p] = (unsigned char)(pk & 0xFF);
    }
  }
  __syncthreads();

  // gather (wave per node, full 64-lane rows); post into hpost
  const float bcol = bias[lane], pwc = pw[lane];
  for (int n = wave; n < 100; n += 8) {
    int e = off[n], end = off[n + 1];
    float a0 = hl[n * 64 + lane], a1 = 0.f;
    for (; e + 1 < end; e += 2) {
      a0 += hl[csr[e] * 64 + lane];
      a1 += hl[csr[e + 1] * 64 + lane];
    }
    if (e < end) a0 += hl[csr[e] * 64 + lane];
    float o = fmaxf(fmaf(a0 + a1, dinv[n], bcol), 0.f);
    hpost[n * 64 + lane] = o;
    float sd = o * pwc;
#pragma unroll
    for (int o2 = 32; o2; o2 >>= 1) sd += __shfl_xor(sd, o2);
    if (lane == 0) sc[n] = sd;
  }
  __syncthreads();

  if (tid < 100) sc[tid] = tanhf(sc[tid] / nrm_s);
  __syncthreads();
  if (tid < 100) {
    float si = sc[tid];
    int r = 0;
    for (int j = 0; j < 100; ++j) {
      float sj = sc[j];
      r += (sj > si) || (sj == si && j < tid);
    }
    nmap2[n0 + tid] = (r < 25) ? (g * 25 + r) : -1;
    if (r < 25) sel[r] = tid;
  }
  __syncthreads();

  if (tid < 400) {
    int r = tid >> 4, c4 = (tid & 15) * 4;
    int n = sel[r];
    float s = sc[n];
    float4 v = *reinterpret_cast<const float4*>(&hpost[n * 64 + c4]);
    v.x *= s; v.y *= s; v.z *= s; v.w *= s;
    *reinterpret_cast<float4*>(&hp2[((size_t)g * 25 + r) * 64 + c4]) = v;
    *reinterpret_cast<float4*>(&red[r][c4]) = v;
  }
  __syncthreads();
  if (tid < 64) {
    float s = 0.f;
    for (int r = 0; r < 25; ++r) s += red[r][tid];
    rsum[g * 64 + tid] = s;
  }
}

// ---------------------------------------------------------------------------
// Stage-3: fused gemm (hp2@W3) + conv + r3 column-sum + final linear.
// ---------------------------------------------------------------------------
__global__ __launch_bounds__(512) void gcn_conv3_final(
    const float* __restrict__ hp,
    const int* __restrict__ src, const int* __restrict__ dst,
    const int* __restrict__ nmap1, const int* __restrict__ nmap2,
    const float* __restrict__ W, const float* __restrict__ bias,
    const float* __restrict__ r1, const float* __restrict__ r2,
    const float* __restrict__ Wl, const float* __restrict__ bl,
    float* __restrict__ out) {
  __shared__ float          Ws[64 * 64];
  __shared__ float          hl[25 * 64];
  __shared__ unsigned char  csr[EPG];
  __shared__ int            deg[25];
  __shared__ float          dinv[25];
  __shared__ int            off[25];
  __shared__ float          rsw[8][64];
  const int g = blockIdx.x, tid = threadIdx.x;
  const int lane = tid & 63, wave = tid >> 6;
  const int e0 = g * EPG, n0 = g * 25;

  for (int i = tid; i < 4096; i += 512) Ws[i] = W[i];
  if (tid < 25) deg[tid] = 0;
  __syncthreads();

  int epack[13];
#pragma unroll
  for (int u = 0; u < 13; ++u) {
    int e = tid + u * 512;
    int pk = -1;
    if (e < EPG) {
      int ns = nmap1[src[e0 + e]], nd = nmap1[dst[e0 + e]];
      if ((ns | nd) >= 0) {
        int ns2 = nmap2[ns], nd2 = nmap2[nd];
        if ((ns2 | nd2) >= 0) {
          int ls = ns2 - n0, ld = nd2 - n0;
          pk = ls | (ld << 16);
          atomicAdd(&deg[ld], 1);
        }
      }
    }
    epack[u] = pk;
  }
  __syncthreads();

  if (tid < 25) {
    dinv[tid] = 1.0f / sqrtf((float)deg[tid] + 1.0f);
    int s = 0;
    for (int j = 0; j < tid; ++j) s += deg[j];
    off[tid] = s;
  }
  __syncthreads();

  for (int n = wave; n < 25; n += 16) {
    int n2 = n + 8;
    float rv  = hp[(size_t)(n0 + n) * 64 + lane];
    float rv2 = (n2 < 25) ? hp[(size_t)(n0 + n2) * 64 + lane] : 0.f;
    float a = 0.f, a2 = 0.f;
#pragma unroll
    for (int k = 0; k < 64; ++k) {
      float w = Ws[k * 64 + lane];
      a  = fmaf(__shfl(rv,  k), w, a);
      a2 = fmaf(__shfl(rv2, k), w, a2);
    }
    hl[n * 64 + lane] = dinv[n] * a;
    if (n2 < 25) hl[n2 * 64 + lane] = dinv[n2] * a2;
  }
#pragma unroll
  for (int u = 0; u < 13; ++u) {
    int pk = epack[u];
    if (pk != -1) {
      int p = atomicAdd(&off[pk >> 16], 1);
      csr[p] = (unsigned char)(pk & 0xFF);
    }
  }
  __syncthreads();

  const float bcol = bias[lane];
  float part = 0.f;
  for (int n = wave; n < 25; n += 8) {
    int end = off[n], e = end - deg[n];
    float a0 = hl[n * 64 + lane], a1 = 0.f;
    for (; e + 1 < end; e += 2) {
      a0 += hl[csr[e] * 64 + lane];
      a1 += hl[csr[e + 1] * 64 + lane];
    }
    if (e < end) a0 += hl[csr[e] * 64 + lane];
    part += fmaxf(fmaf(a0 + a1, dinv[n], bcol), 0.f);
  }
  rsw[wave][lane] = part;
  __syncthreads();

  if (tid < 64) {
    float r3c = ((rsw[0][tid] + rsw[1][tid]) + (rsw[2][tid] + rsw[3][tid]))
              + ((rsw[4][tid] + rsw[5][tid]) + (rsw[6][tid] + rsw[7][tid]));
    float f1 = r2[g * 64 + tid];
    float f2 = r1[g * 64 + tid];
    float p0 = r3c * Wl[tid * 2 + 0] + f1 * Wl[(64 + tid) * 2 + 0] + f2 * Wl[(128 + tid) * 2 + 0];
    float p1 = r3c * Wl[tid * 2 + 1] + f1 * Wl[(64 + tid) * 2 + 1] + f2 * Wl[(128 + tid) * 2 + 1];
#pragma unroll
    for (int o = 32; o; o >>= 1) {
      p0 += __shfl_xor(p0, o);
      p1 += __shfl_xor(p1, o);
    }
    if (tid == 0) {
      out[g * 2 + 0] = p0 + bl[0];
      out[g * 2 + 1] = p1 + bl[1];
    }
  }
}

// ---------------------------------------------------------------------------
extern "C" void kernel_launch(void* const* d_in, const int* in_sizes, int n_in,
                              void* d_out, int out_size, void* d_ws, size_t ws_size,
                              hipStream_t stream) {
  const float* x   = (const float*)d_in[0];
  const int*   src = (const int*)d_in[1];
  const int*   dst = (const int*)d_in[2];
  const float* W1  = (const float*)d_in[4];
  const float* b1  = (const float*)d_in[5];
  const float* W2  = (const float*)d_in[6];
  const float* b2  = (const float*)d_in[7];
  const float* W3  = (const float*)d_in[8];
  const float* b3  = (const float*)d_in[9];
  const float* pw1 = (const float*)d_in[10];
  const float* pw2 = (const float*)d_in[11];
  const float* Wl  = (const float*)d_in[12];
  const float* bl  = (const float*)d_in[13];
  float* out = (float*)d_out;

  float* ws    = (float*)d_ws;
  float* h1    = ws;                                  // 6,553,600 f
  float* hp1   = h1 + (size_t)102400 * 64;            // 1,638,400 f
  float* hp2   = hp1 + (size_t)25600 * 64;            //   409,600 f
  int*   nmap1 = (int*)(hp2 + (size_t)6400 * 64);     //   102,400 i
  int*   nmap2 = nmap1 + 102400;                      //    25,600 i
  float* r1    = (float*)(nmap2 + 25600);             //    16,384 f
  float* r2    = r1 + 16384;                          //    16,384 f

  gemm64<128><<<102400 / 64, 256, 0, stream>>>(x, W1, h1);
  fused_stage1<<<BGR, 1024, 0, stream>>>(h1, src, dst, b1, pw1, hp1, nmap1, r1);
  fused_stage2<<<BGR, 512, 0, stream>>>(hp1, src, dst, nmap1, W2, b2, pw2,
                                        hp2, nmap2, r2);
  gcn_conv3_final<<<BGR, 512, 0, stream>>>(hp2, src, dst, nmap1, nmap2,
                                           W3, b3, r1, r2, Wl, bl, out);
}

// Round 7
// 166.140 us; speedup vs baseline: 1.3059x; 1.0110x over previous
//
#include <hip/hip_runtime.h>
#include <hip/hip_bf16.h>
#include <math.h>

#define BGR  256      // graphs
#define NN   400      // nodes per graph (stage 1)
#define EPG  6400     // edges per graph

// ---------------------------------------------------------------------------
// GEMM: H[M x 64] = X[M x K] @ W[K x 64], M multiple of 64, f32.
// ---------------------------------------------------------------------------
template<int K>
__global__ __launch_bounds__(256) void gemm64(const float* __restrict__ X,
                                              const float* __restrict__ W,
                                              float* __restrict__ H) {
  __shared__ float xs[64][K + 8];
  const int m0 = blockIdx.x * 64;
  for (int i = threadIdx.x; i < 64 * (K / 4); i += 256) {
    int m = i / (K / 4), q = i % (K / 4);
    float4 v = *reinterpret_cast<const float4*>(X + (size_t)(m0 + m) * K + q * 4);
    *reinterpret_cast<float4*>(&xs[m][q * 4]) = v;
  }
  __syncthreads();
  const int c = threadIdx.x & 63;
  const int mg = (threadIdx.x >> 6) * 16;
  float acc[16];
#pragma unroll
  for (int i = 0; i < 16; ++i) acc[i] = 0.f;
  for (int k = 0; k < K; k += 4) {
    float w0 = W[(k + 0) * 64 + c];
    float w1 = W[(k + 1) * 64 + c];
    float w2 = W[(k + 2) * 64 + c];
    float w3 = W[(k + 3) * 64 + c];
#pragma unroll
    for (int i = 0; i < 16; ++i) {
      float4 xv = *reinterpret_cast<const float4*>(&xs[mg + i][k]);
      float a = acc[i];
      a = fmaf(xv.x, w0, a);
      a = fmaf(xv.y, w1, a);
      a = fmaf(xv.z, w2, a);
      a = fmaf(xv.w, w3, a);
      acc[i] = a;
    }
  }
#pragma unroll
  for (int i = 0; i < 16; ++i)
    H[(size_t)(m0 + mg + i) * 64 + c] = acc[i];
}

// ---------------------------------------------------------------------------
// Stage 1 mega-kernel, one block per graph (1024 threads).
// Gather: wave-per-node, lane=channel, ds_read_b32 rows (stride-1, 2-way
// bank aliasing = free) + broadcast u32 CSR reads. h1 prefetched to regs
// under the edge/scan phases. Conv + topk + hp1/nmap1/r1 fused.
// ---------------------------------------------------------------------------
__global__ __launch_bounds__(1024, 4) void fused_stage1(
    const float* __restrict__ h1,
    const int* __restrict__ src, const int* __restrict__ dst,
    const float* __restrict__ bias, const float* __restrict__ pw,
    float* __restrict__ hp1, int* __restrict__ nmap, float* __restrict__ rsum) {
  __shared__ float          hl[NN * 64];      // 102400 B
  __shared__ unsigned short csr[EPG];         // 12800 B (src local id * 64)
  __shared__ int            off[NN + 1];
  __shared__ int            cur[NN];
  __shared__ int            deg[NN];
  __shared__ float          dinv[NN];
  __shared__ float          sc[NN];
  __shared__ int            sel[100];
  __shared__ float          red16[16][64];    // 4096 B
  __shared__ int            wpart[8];
  __shared__ float          nrm_s;

  const int g = blockIdx.x;
  const int tid = threadIdx.x;
  const int lane = tid & 63, wave = tid >> 6;
  const int e0 = g * EPG;
  const size_t hbase = (size_t)g * NN * 64;

  for (int i = tid; i < NN; i += 1024) deg[i] = 0;
  if (tid < 64) {                              // ||pw||
    float p = pw[tid];
    float t = p * p;
#pragma unroll
    for (int o = 32; o; o >>= 1) t += __shfl_xor(t, o);
    if (tid == 0) nrm_s = sqrtf(t);
  }
  __syncthreads();

  // ---- issue edge loads, then h1 prefetch (overlaps edge/atomic phases) ----
  int els[7], eld[7];
#pragma unroll
  for (int u = 0; u < 7; ++u) {
    int e = tid + u * 1024;
    if (e < EPG) {
      els[u] = src[e0 + e] - g * NN;
      eld[u] = dst[e0 + e] - g * NN;
    } else {
      els[u] = 0; eld[u] = -1;
    }
  }
  float4 hreg[7];
#pragma unroll
  for (int u = 0; u < 7; ++u) {
    int i = tid + u * 1024;
    if (i < NN * 16)
      hreg[u] = *reinterpret_cast<const float4*>(&h1[hbase + (size_t)i * 4]);
  }

  // ---- degree ----
#pragma unroll
  for (int u = 0; u < 7; ++u)
    if (eld[u] >= 0) atomicAdd(&deg[eld[u]], 1);
  __syncthreads();

  // ---- parallel exclusive scan of deg -> off/cur; dinv ----
  int myincl = 0, myd = 0;
  if (tid < NN) {
    myd = deg[tid];
    int v = myd;
#pragma unroll
    for (int o = 1; o < 64; o <<= 1) {
      int t = __shfl_up(v, o);
      if ((tid & 63) >= o) v += t;
    }
    myincl = v;
    dinv[tid] = 1.0f / sqrtf((float)myd + 1.0f);
    if ((tid & 63) == 63 || tid == NN - 1) wpart[tid >> 6] = v;
  }
  __syncthreads();
  if (tid < NN) {
    int base = 0;
    int w = tid >> 6;
    for (int j = 0; j < w; ++j) base += wpart[j];
    int incl = base + myincl;
    off[tid + 1] = incl;
    cur[tid] = incl - myd;
    if (tid == 0) off[0] = 0;
  }
  __syncthreads();

  // ---- stage scaled h from regs + fill CSR ----
#pragma unroll
  for (int u = 0; u < 7; ++u) {
    int i = tid + u * 1024;
    if (i < NN * 16) {
      int n = i >> 4;
      float dn = dinv[n];
      float4 v = hreg[u];
      v.x *= dn; v.y *= dn; v.z *= dn; v.w *= dn;
      *reinterpret_cast<float4*>(&hl[i * 4]) = v;
    }
  }
#pragma unroll
  for (int u = 0; u < 7; ++u) {
    if (eld[u] >= 0) {
      int p = atomicAdd(&cur[eld[u]], 1);
      csr[p] = (unsigned short)(els[u] << 6);   // premult by 64
    }
  }
  __syncthreads();

  // ---- gather: wave-per-node, lane = channel, b32 rows ----
  const float bcol = bias[lane];
  float outv[25];
#pragma unroll
  for (int it = 0; it < 25; ++it) {
    int n = (it << 4) + wave;                  // 400 = 25 * 16 waves
    int e = off[n], end = off[n + 1];
    float a0 = hl[(n << 6) + lane];            // self term
    float a1 = 0.f, a2 = 0.f, a3 = 0.f;
    if (e < end && (e & 1)) {                  // peel to even
      a1 += hl[csr[e] + lane];
      ++e;
    }
    while (e + 4 <= end) {
      unsigned p0 = *reinterpret_cast<const unsigned*>(&csr[e]);
      unsigned p1 = *reinterpret_cast<const unsigned*>(&csr[e + 2]);
      a0 += hl[(p0 & 0xFFFF) + lane];
      a1 += hl[(p0 >> 16) + lane];
      a2 += hl[(p1 & 0xFFFF) + lane];
      a3 += hl[(p1 >> 16) + lane];
      e += 4;
    }
    if (e + 2 <= end) {
      unsigned p0 = *reinterpret_cast<const unsigned*>(&csr[e]);
      a0 += hl[(p0 & 0xFFFF) + lane];
      a1 += hl[(p0 >> 16) + lane];
      e += 2;
    }
    if (e < end) a2 += hl[csr[e] + lane];
    outv[it] = fmaxf(fmaf((a0 + a1) + (a2 + a3), dinv[n], bcol), 0.f);
  }
  __syncthreads();   // all reads of hl done

  // ---- writeback post into hl ----
#pragma unroll
  for (int it = 0; it < 25; ++it) {
    int n = (it << 4) + wave;
    hl[(n << 6) + lane] = outv[it];
  }
  __syncthreads();

  // ---- scores: linear b128 reads (contiguous rows per wave) ----
  const int l16 = tid & 15;
  const float4 pw4 = *reinterpret_cast<const float4*>(&pw[l16 * 4]);
#pragma unroll
  for (int it = 0; it < 7; ++it) {
    int idx = it * 1024 + tid;
    if (idx < NN * 16) {
      int n = idx >> 4;
      float4 v = *reinterpret_cast<const float4*>(&hl[idx * 4]);
      float sd = v.x * pw4.x + v.y * pw4.y + v.z * pw4.z + v.w * pw4.w;
      sd += __shfl_xor(sd, 1);
      sd += __shfl_xor(sd, 2);
      sd += __shfl_xor(sd, 4);
      sd += __shfl_xor(sd, 8);
      if (l16 == 0) sc[n] = sd;
    }
  }
  __syncthreads();
  if (tid < NN) sc[tid] = tanhf(sc[tid] / nrm_s);
  __syncthreads();

  // ---- stable rank top-100 ----
  if (tid < NN) {
    float si = sc[tid];
    int r = 0;
    for (int j = 0; j < NN; ++j) {
      float sj = sc[j];
      r += (sj > si) || (sj == si && j < tid);
    }
    nmap[g * NN + tid] = (r < 100) ? (g * 100 + r) : -1;
    if (r < 100) sel[r] = tid;
  }
  __syncthreads();

  // ---- hp1 write + r1 column sums (deterministic shfl tree) ----
  {
    int r = tid >> 4;                   // 0..63
    int c4 = (tid & 15) * 4;
    int n = sel[r];
    float s = sc[n];
    float4 v = *reinterpret_cast<const float4*>(&hl[(n << 6) + c4]);
    v.x *= s; v.y *= s; v.z *= s; v.w *= s;
    *reinterpret_cast<float4*>(&hp1[((size_t)g * 100 + r) * 64 + c4]) = v;
    if (tid < 576) {                    // rows 64..99
      int r2 = 64 + r;
      int n2 = sel[r2];
      float s2 = sc[n2];
      float4 v2 = *reinterpret_cast<const float4*>(&hl[(n2 << 6) + c4]);
      v2.x *= s2; v2.y *= s2; v2.z *= s2; v2.w *= s2;
      *reinterpret_cast<float4*>(&hp1[((size_t)g * 100 + r2) * 64 + c4]) = v2;
      v.x += v2.x; v.y += v2.y; v.z += v2.z; v.w += v2.w;
    }
    v.x += __shfl_xor(v.x, 16); v.y += __shfl_xor(v.y, 16);
    v.z += __shfl_xor(v.z, 16); v.w += __shfl_xor(v.w, 16);
    v.x += __shfl_xor(v.x, 32); v.y += __shfl_xor(v.y, 32);
    v.z += __shfl_xor(v.z, 32); v.w += __shfl_xor(v.w, 32);
    if ((lane & 48) == 0)
      *reinterpret_cast<float4*>(&red16[wave][c4]) = v;
  }
  __syncthreads();
  if (tid < 64) {
    float s = 0.f;
#pragma unroll
    for (int w2 = 0; w2 < 16; ++w2) s += red16[w2][tid];
    rsum[g * 64 + tid] = s;
  }
}

// ---------------------------------------------------------------------------
// Stage 2 mega-kernel: gemm (hp1@W2) + conv + topk + hp2 / nmap2 / r2.
// One block (512 thr) per graph. Ws aliases hpost (dead by gather phase).
// ---------------------------------------------------------------------------
__global__ __launch_bounds__(512) void fused_stage2(
    const float* __restrict__ hp,
    const int* __restrict__ src, const int* __restrict__ dst,
    const int* __restrict__ nmap1,
    const float* __restrict__ W, const float* __restrict__ bias,
    const float* __restrict__ pw,
    float* __restrict__ hp2, int* __restrict__ nmap2, float* __restrict__ rsum) {
  __shared__ float          hl[100 * 64];     // pre (dinv-scaled gemm out)
  __shared__ float          hpost[100 * 64];  // post; first 4096 floats = Ws
  __shared__ unsigned char  csr[EPG];
  __shared__ int            deg[100];
  __shared__ float          dinv[100];
  __shared__ int            off[101];
  __shared__ int            cur[100];
  __shared__ float          sc[100];
  __shared__ int            sel[25];
  __shared__ float          red[25][64];
  __shared__ float          nrm_s;
  float* Ws = hpost;                          // alias (16 KB)

  const int g = blockIdx.x, tid = threadIdx.x;
  const int lane = tid & 63, wave = tid >> 6;
  const int e0 = g * EPG, n0 = g * 100;

  for (int i = tid; i < 4096; i += 512) Ws[i] = W[i];
  if (tid < 100) deg[tid] = 0;
  if (wave == 7) {
    float p = pw[lane];
    float t = p * p;
#pragma unroll
    for (int o = 32; o; o >>= 1) t += __shfl_xor(t, o);
    if (lane == 0) nrm_s = sqrtf(t);
  }
  __syncthreads();

  int epack[13];
#pragma unroll
  for (int u = 0; u < 13; ++u) {
    int e = tid + u * 512;
    int pk = -1;
    if (e < EPG) {
      int ns = nmap1[src[e0 + e]], nd = nmap1[dst[e0 + e]];
      if ((ns | nd) >= 0) {
        pk = (ns - n0) | ((nd - n0) << 16);
        atomicAdd(&deg[nd - n0], 1);
      }
    }
    epack[u] = pk;
  }
  __syncthreads();

  if (tid < 100) {
    int d = deg[tid];
    dinv[tid] = 1.0f / sqrtf((float)d + 1.0f);
    int s = 0;
    for (int j = 0; j < tid; ++j) s += deg[j];
    off[tid] = s;
    cur[tid] = s;
    if (tid == 99) off[100] = s + d;
  }
  __syncthreads();

  // gemm into hl (scaled); csr fill
  for (int n = wave; n < 100; n += 16) {
    int n2 = n + 8;
    float rv  = hp[(size_t)(n0 + n) * 64 + lane];
    float rv2 = (n2 < 100) ? hp[(size_t)(n0 + n2) * 64 + lane] : 0.f;
    float a = 0.f, a2 = 0.f;
#pragma unroll
    for (int k = 0; k < 64; ++k) {
      float w = Ws[k * 64 + lane];
      a  = fmaf(__shfl(rv,  k), w, a);
      a2 = fmaf(__shfl(rv2, k), w, a2);
    }
    hl[n * 64 + lane] = dinv[n] * a;
    if (n2 < 100) hl[n2 * 64 + lane] = dinv[n2] * a2;
  }
#pragma unroll
  for (int u = 0; u < 13; ++u) {
    int pk = epack[u];
    if (pk != -1) {
      int p = atomicAdd(&cur[pk >> 16], 1);
      csr[p] = (unsigned char)(pk & 0xFF);
    }
  }
  __syncthreads();

  // gather (wave per node, full 64-lane rows); post into hpost
  const float bcol = bias[lane], pwc = pw[lane];
  for (int n = wave; n < 100; n += 8) {
    int e = off[n], end = off[n + 1];
    float a0 = hl[n * 64 + lane], a1 = 0.f;
    for (; e + 1 < end; e += 2) {
      a0 += hl[csr[e] * 64 + lane];
      a1 += hl[csr[e + 1] * 64 + lane];
    }
    if (e < end) a0 += hl[csr[e] * 64 + lane];
    float o = fmaxf(fmaf(a0 + a1, dinv[n], bcol), 0.f);
    hpost[n * 64 + lane] = o;
    float sd = o * pwc;
#pragma unroll
    for (int o2 = 32; o2; o2 >>= 1) sd += __shfl_xor(sd, o2);
    if (lane == 0) sc[n] = sd;
  }
  __syncthreads();

  if (tid < 100) sc[tid] = tanhf(sc[tid] / nrm_s);
  __syncthreads();
  if (tid < 100) {
    float si = sc[tid];
    int r = 0;
    for (int j = 0; j < 100; ++j) {
      float sj = sc[j];
      r += (sj > si) || (sj == si && j < tid);
    }
    nmap2[n0 + tid] = (r < 25) ? (g * 25 + r) : -1;
    if (r < 25) sel[r] = tid;
  }
  __syncthreads();

  if (tid < 400) {
    int r = tid >> 4, c4 = (tid & 15) * 4;
    int n = sel[r];
    float s = sc[n];
    float4 v = *reinterpret_cast<const float4*>(&hpost[n * 64 + c4]);
    v.x *= s; v.y *= s; v.z *= s; v.w *= s;
    *reinterpret_cast<float4*>(&hp2[((size_t)g * 25 + r) * 64 + c4]) = v;
    *reinterpret_cast<float4*>(&red[r][c4]) = v;
  }
  __syncthreads();
  if (tid < 64) {
    float s = 0.f;
    for (int r = 0; r < 25; ++r) s += red[r][tid];
    rsum[g * 64 + tid] = s;
  }
}

// ---------------------------------------------------------------------------
// Stage-3: fused gemm (hp2@W3) + conv + r3 column-sum + final linear.
// ---------------------------------------------------------------------------
__global__ __launch_bounds__(512) void gcn_conv3_final(
    const float* __restrict__ hp,
    const int* __restrict__ src, const int* __restrict__ dst,
    const int* __restrict__ nmap1, const int* __restrict__ nmap2,
    const float* __restrict__ W, const float* __restrict__ bias,
    const float* __restrict__ r1, const float* __restrict__ r2,
    const float* __restrict__ Wl, const float* __restrict__ bl,
    float* __restrict__ out) {
  __shared__ float          Ws[64 * 64];
  __shared__ float          hl[25 * 64];
  __shared__ unsigned char  csr[EPG];
  __shared__ int            deg[25];
  __shared__ float          dinv[25];
  __shared__ int            off[25];
  __shared__ float          rsw[8][64];
  const int g = blockIdx.x, tid = threadIdx.x;
  const int lane = tid & 63, wave = tid >> 6;
  const int e0 = g * EPG, n0 = g * 25;

  for (int i = tid; i < 4096; i += 512) Ws[i] = W[i];
  if (tid < 25) deg[tid] = 0;
  __syncthreads();

  int epack[13];
#pragma unroll
  for (int u = 0; u < 13; ++u) {
    int e = tid + u * 512;
    int pk = -1;
    if (e < EPG) {
      int ns = nmap1[src[e0 + e]], nd = nmap1[dst[e0 + e]];
      if ((ns | nd) >= 0) {
        int ns2 = nmap2[ns], nd2 = nmap2[nd];
        if ((ns2 | nd2) >= 0) {
          int ls = ns2 - n0, ld = nd2 - n0;
          pk = ls | (ld << 16);
          atomicAdd(&deg[ld], 1);
        }
      }
    }
    epack[u] = pk;
  }
  __syncthreads();

  if (tid < 25) {
    dinv[tid] = 1.0f / sqrtf((float)deg[tid] + 1.0f);
    int s = 0;
    for (int j = 0; j < tid; ++j) s += deg[j];
    off[tid] = s;
  }
  __syncthreads();

  for (int n = wave; n < 25; n += 16) {
    int n2 = n + 8;
    float rv  = hp[(size_t)(n0 + n) * 64 + lane];
    float rv2 = (n2 < 25) ? hp[(size_t)(n0 + n2) * 64 + lane] : 0.f;
    float a = 0.f, a2 = 0.f;
#pragma unroll
    for (int k = 0; k < 64; ++k) {
      float w = Ws[k * 64 + lane];
      a  = fmaf(__shfl(rv,  k), w, a);
      a2 = fmaf(__shfl(rv2, k), w, a2);
    }
    hl[n * 64 + lane] = dinv[n] * a;
    if (n2 < 25) hl[n2 * 64 + lane] = dinv[n2] * a2;
  }
#pragma unroll
  for (int u = 0; u < 13; ++u) {
    int pk = epack[u];
    if (pk != -1) {
      int p = atomicAdd(&off[pk >> 16], 1);
      csr[p] = (unsigned char)(pk & 0xFF);
    }
  }
  __syncthreads();

  const float bcol = bias[lane];
  float part = 0.f;
  for (int n = wave; n < 25; n += 8) {
    int end = off[n], e = end - deg[n];
    float a0 = hl[n * 64 + lane], a1 = 0.f;
    for (; e + 1 < end; e += 2) {
      a0 += hl[csr[e] * 64 + lane];
      a1 += hl[csr[e + 1] * 64 + lane];
    }
    if (e < end) a0 += hl[csr[e] * 64 + lane];
    part += fmaxf(fmaf(a0 + a1, dinv[n], bcol), 0.f);
  }
  rsw[wave][lane] = part;
  __syncthreads();

  if (tid < 64) {
    float r3c = ((rsw[0][tid] + rsw[1][tid]) + (rsw[2][tid] + rsw[3][tid]))
              + ((rsw[4][tid] + rsw[5][tid]) + (rsw[6][tid] + rsw[7][tid]));
    float f1 = r2[g * 64 + tid];
    float f2 = r1[g * 64 + tid];
    float p0 = r3c * Wl[tid * 2 + 0] + f1 * Wl[(64 + tid) * 2 + 0] + f2 * Wl[(128 + tid) * 2 + 0];
    float p1 = r3c * Wl[tid * 2 + 1] + f1 * Wl[(64 + tid) * 2 + 1] + f2 * Wl[(128 + tid) * 2 + 1];
#pragma unroll
    for (int o = 32; o; o >>= 1) {
      p0 += __shfl_xor(p0, o);
      p1 += __shfl_xor(p1, o);
    }
    if (tid == 0) {
      out[g * 2 + 0] = p0 + bl[0];
      out[g * 2 + 1] = p1 + bl[1];
    }
  }
}

// ---------------------------------------------------------------------------
extern "C" void kernel_launch(void* const* d_in, const int* in_sizes, int n_in,
                              void* d_out, int out_size, void* d_ws, size_t ws_size,
                              hipStream_t stream) {
  const float* x   = (const float*)d_in[0];
  const int*   src = (const int*)d_in[1];
  const int*   dst = (const int*)d_in[2];
  const float* W1  = (const float*)d_in[4];
  const float* b1  = (const float*)d_in[5];
  const float* W2  = (const float*)d_in[6];
  const float* b2  = (const float*)d_in[7];
  const float* W3  = (const float*)d_in[8];
  const float* b3  = (const float*)d_in[9];
  const float* pw1 = (const float*)d_in[10];
  const float* pw2 = (const float*)d_in[11];
  const float* Wl  = (const float*)d_in[12];
  const float* bl  = (const float*)d_in[13];
  float* out = (float*)d_out;

  float* ws    = (float*)d_ws;
  float* h1    = ws;                                  // 6,553,600 f
  float* hp1   = h1 + (size_t)102400 * 64;            // 1,638,400 f
  float* hp2   = hp1 + (size_t)25600 * 64;            //   409,600 f
  int*   nmap1 = (int*)(hp2 + (size_t)6400 * 64);     //   102,400 i
  int*   nmap2 = nmap1 + 102400;                      //    25,600 i
  float* r1    = (float*)(nmap2 + 25600);             //    16,384 f
  float* r2    = r1 + 16384;                          //    16,384 f

  gemm64<128><<<102400 / 64, 256, 0, stream>>>(x, W1, h1);
  fused_stage1<<<BGR, 1024, 0, stream>>>(h1, src, dst, b1, pw1, hp1, nmap1, r1);
  fused_stage2<<<BGR, 512, 0, stream>>>(hp1, src, dst, nmap1, W2, b2, pw2,
                                        hp2, nmap2, r2);
  gcn_conv3_final<<<BGR, 512, 0, stream>>>(hp2, src, dst, nmap1, nmap2,
                                           W3, b3, r1, r2, Wl, bl, out);
}

// Round 8
// 138.079 us; speedup vs baseline: 1.5713x; 1.2032x over previous
//
#include <hip/hip_runtime.h>
#include <math.h>

#define BGR  256      // graphs
#define NN   400      // nodes per graph (stage 1)
#define EPG  6400     // edges per graph

// ---------------------------------------------------------------------------
// GEMM: H[M x 64] = X[M x K] @ W[K x 64], M multiple of 64, f32.
// ---------------------------------------------------------------------------
template<int K>
__global__ __launch_bounds__(256) void gemm64(const float* __restrict__ X,
                                              const float* __restrict__ W,
                                              float* __restrict__ H) {
  __shared__ float xs[64][K + 8];
  const int m0 = blockIdx.x * 64;
  for (int i = threadIdx.x; i < 64 * (K / 4); i += 256) {
    int m = i / (K / 4), q = i % (K / 4);
    float4 v = *reinterpret_cast<const float4*>(X + (size_t)(m0 + m) * K + q * 4);
    *reinterpret_cast<float4*>(&xs[m][q * 4]) = v;
  }
  __syncthreads();
  const int c = threadIdx.x & 63;
  const int mg = (threadIdx.x >> 6) * 16;
  float acc[16];
#pragma unroll
  for (int i = 0; i < 16; ++i) acc[i] = 0.f;
  for (int k = 0; k < K; k += 4) {
    float w0 = W[(k + 0) * 64 + c];
    float w1 = W[(k + 1) * 64 + c];
    float w2 = W[(k + 2) * 64 + c];
    float w3 = W[(k + 3) * 64 + c];
#pragma unroll
    for (int i = 0; i < 16; ++i) {
      float4 xv = *reinterpret_cast<const float4*>(&xs[mg + i][k]);
      float a = acc[i];
      a = fmaf(xv.x, w0, a);
      a = fmaf(xv.y, w1, a);
      a = fmaf(xv.z, w2, a);
      a = fmaf(xv.w, w3, a);
      acc[i] = a;
    }
  }
#pragma unroll
  for (int i = 0; i < 16; ++i)
    H[(size_t)(m0 + mg + i) * 64 + c] = acc[i];
}

// ---------------------------------------------------------------------------
// Mega-kernel: stages 1+2+3 fused, one block (1024 thr) per graph.
// Edges held in registers across stages; all intermediates in LDS.
// Padded CSR (x8 stage1 / x4 stages 2,3) -> uint4/uint2 broadcast index
// reads + independent conflict-free b32 row gathers.
// ---------------------------------------------------------------------------
__global__ __launch_bounds__(1024, 4) void mega(
    const float* __restrict__ h1,
    const int* __restrict__ src, const int* __restrict__ dst,
    const float* __restrict__ b1, const float* __restrict__ pw1,
    const float* __restrict__ W2, const float* __restrict__ b2,
    const float* __restrict__ pw2,
    const float* __restrict__ W3, const float* __restrict__ b3,
    const float* __restrict__ Wl, const float* __restrict__ bl,
    float* __restrict__ out) {
  __shared__ float hl[401 * 64];                       // 102,656 B (row 400 = 0)
  __shared__ __align__(16) unsigned short csr[9216];   // 18,432 B
  __shared__ int   off[NN + 1];
  __shared__ int   cur[NN];
  __shared__ float dinv[NN];
  __shared__ float sc[NN];
  __shared__ int   sel[100];
  __shared__ int   lmap[NN];
  __shared__ float hp[100 * 64];                       // 25,600 B
  __shared__ float r1s[64], r2s[64];
  __shared__ int   wpart[8];
  __shared__ float nrm1_s, nrm2_s;

  const int g = blockIdx.x, tid = threadIdx.x;
  const int lane = tid & 63, wave = tid >> 6;
  const int e0 = g * EPG;
  const size_t hbase = (size_t)g * NN * 64;

  // ---- init: zero deg (cur), zero row 400, pw norms ----
  for (int i = tid; i < NN; i += 1024) cur[i] = 0;
  if (tid < 64) hl[400 * 64 + tid] = 0.f;
  if (wave == 14) {
    float p = pw1[lane], t = p * p;
#pragma unroll
    for (int o = 32; o; o >>= 1) t += __shfl_xor(t, o);
    if (lane == 0) nrm1_s = sqrtf(t);
  }
  if (wave == 15) {
    float p = pw2[lane], t = p * p;
#pragma unroll
    for (int o = 32; o; o >>= 1) t += __shfl_xor(t, o);
    if (lane == 0) nrm2_s = sqrtf(t);
  }
  __syncthreads();

  // ---- edges to regs + h1 prefetch + degree ----
  int es[7], ed[7];
#pragma unroll
  for (int u = 0; u < 7; ++u) {
    int e = tid + u * 1024;
    if (e < EPG) { es[u] = src[e0 + e] - g * NN; ed[u] = dst[e0 + e] - g * NN; }
    else         { es[u] = 0; ed[u] = -1; }
  }
  float4 hreg[7];
#pragma unroll
  for (int u = 0; u < 7; ++u) {
    int i = tid + u * 1024;
    if (i < NN * 16)
      hreg[u] = *reinterpret_cast<const float4*>(&h1[hbase + (size_t)i * 4]);
  }
#pragma unroll
  for (int u = 0; u < 7; ++u)
    if (ed[u] >= 0) atomicAdd(&cur[ed[u]], 1);
  __syncthreads();

  // ---- scan of padded degrees (x8); dinv ----
  int vincl = 0, myp = 0;
  if (tid < NN) {
    int d = cur[tid];
    dinv[tid] = 1.0f / sqrtf((float)d + 1.0f);
    myp = (d + 7) & ~7;
    vincl = myp;
#pragma unroll
    for (int o = 1; o < 64; o <<= 1) {
      int t = __shfl_up(vincl, o);
      if ((tid & 63) >= o) vincl += t;
    }
    if ((tid & 63) == 63 || tid == NN - 1) wpart[tid >> 6] = vincl;
  }
  __syncthreads();
  if (tid < NN) {
    int base = 0, w = tid >> 6;
    for (int j = 0; j < w; ++j) base += wpart[j];
    int incl = base + vincl;
    off[tid + 1] = incl;
    cur[tid] = incl - myp;
    if (tid == 0) off[0] = 0;
  }
  __syncthreads();

  // ---- stage hl (dinv-scaled) + csr fill ----
#pragma unroll
  for (int u = 0; u < 7; ++u) {
    int i = tid + u * 1024;
    if (i < NN * 16) {
      int n = i >> 4;
      float dn = dinv[n];
      float4 vv = hreg[u];
      vv.x *= dn; vv.y *= dn; vv.z *= dn; vv.w *= dn;
      *reinterpret_cast<float4*>(&hl[i * 4]) = vv;
    }
  }
#pragma unroll
  for (int u = 0; u < 7; ++u)
    if (ed[u] >= 0) {
      int p = atomicAdd(&cur[ed[u]], 1);
      csr[p] = (unsigned short)(es[u] << 6);
    }
  __syncthreads();
  if (tid < NN) {
    int pend = off[tid + 1];
    for (int p = cur[tid]; p < pend; ++p) csr[p] = (unsigned short)(400 * 64);
  }
  __syncthreads();

  // ---- gather1: wave-per-node; uint4 csr broadcast -> 8 b32 rows ----
  {
    const float bc1 = b1[lane];
    float outv[25];
#pragma unroll
    for (int it = 0; it < 25; ++it) {
      int n = it * 16 + wave;
      int e = off[n], end = off[n + 1];
      float a0 = hl[(n << 6) + lane], a1 = 0.f, a2 = 0.f, a3 = 0.f;
      for (; e < end; e += 8) {
        uint4 pk = *reinterpret_cast<const uint4*>(&csr[e]);
        a0 += hl[(pk.x & 0xFFFF) + lane];
        a1 += hl[(pk.x >> 16) + lane];
        a2 += hl[(pk.y & 0xFFFF) + lane];
        a3 += hl[(pk.y >> 16) + lane];
        a0 += hl[(pk.z & 0xFFFF) + lane];
        a1 += hl[(pk.z >> 16) + lane];
        a2 += hl[(pk.w & 0xFFFF) + lane];
        a3 += hl[(pk.w >> 16) + lane];
      }
      outv[it] = fmaxf(fmaf((a0 + a1) + (a2 + a3), dinv[n], bc1), 0.f);
    }
    __syncthreads();
#pragma unroll
    for (int it = 0; it < 25; ++it)
      hl[((it * 16 + wave) << 6) + lane] = outv[it];
  }
  __syncthreads();

  // ---- score1 (b128 linear) ----
  {
    const int l16 = tid & 15;
    float4 pwv = *reinterpret_cast<const float4*>(&pw1[l16 * 4]);
#pragma unroll
    for (int it = 0; it < 7; ++it) {
      int idx = it * 1024 + tid;
      if (idx < NN * 16) {
        float4 vv = *reinterpret_cast<const float4*>(&hl[idx * 4]);
        float sd = vv.x * pwv.x + vv.y * pwv.y + vv.z * pwv.z + vv.w * pwv.w;
        sd += __shfl_xor(sd, 1);
        sd += __shfl_xor(sd, 2);
        sd += __shfl_xor(sd, 4);
        sd += __shfl_xor(sd, 8);
        if (l16 == 0) sc[idx >> 4] = sd;
      }
    }
  }
  __syncthreads();
  if (tid < NN) sc[tid] = tanhf(sc[tid] / nrm1_s);
  __syncthreads();

  // ---- rank1 (stable, 2 nodes/thread) ----
  if (tid < 200) {
    int i0 = tid * 2, i1 = i0 + 1;
    float s0 = sc[i0], s1 = sc[i1];
    int rk0 = 0, rk1 = 0;
    for (int j = 0; j < NN; ++j) {
      float sj = sc[j];
      rk0 += (sj > s0) || (sj == s0 && j < i0);
      rk1 += (sj > s1) || (sj == s1 && j < i1);
    }
    lmap[i0] = (rk0 < 100) ? rk0 : -1;
    if (rk0 < 100) sel[rk0] = i0;
    lmap[i1] = (rk1 < 100) ? rk1 : -1;
    if (rk1 < 100) sel[rk1] = i1;
  }
  __syncthreads();

  // ---- hp extract (scaled) + edge remap + zero deg2 ----
  {
    int r = tid >> 4, c4 = (tid & 15) * 4;
    int n = sel[r];
    float s = sc[n];
    float4 vv = *reinterpret_cast<const float4*>(&hl[(n << 6) + c4]);
    vv.x *= s; vv.y *= s; vv.z *= s; vv.w *= s;
    *reinterpret_cast<float4*>(&hp[r * 64 + c4]) = vv;
    if (tid < 576) {
      int r2 = r + 64;
      int n2 = sel[r2];
      float s2 = sc[n2];
      float4 v2 = *reinterpret_cast<const float4*>(&hl[(n2 << 6) + c4]);
      v2.x *= s2; v2.y *= s2; v2.z *= s2; v2.w *= s2;
      *reinterpret_cast<float4*>(&hp[r2 * 64 + c4]) = v2;
    }
  }
#pragma unroll
  for (int u = 0; u < 7; ++u)
    if (ed[u] >= 0) {
      int a = lmap[es[u]], b = lmap[ed[u]];
      if ((a | b) >= 0) { es[u] = a; ed[u] = b; } else ed[u] = -1;
    }
  if (tid >= 512 && tid < 612) cur[tid - 512] = 0;
  __syncthreads();

  // ---- r1 sums + deg2 ----
  if (tid < 64) {
    float s = 0.f;
    for (int r = 0; r < 100; ++r) s += hp[r * 64 + tid];
    r1s[tid] = s;
  }
#pragma unroll
  for (int u = 0; u < 7; ++u)
    if (ed[u] >= 0) atomicAdd(&cur[ed[u]], 1);
  __syncthreads();

  // ---- scan2 (serial, pad x4) ----
  int d2 = 0, st2 = 0;
  if (tid < 100) {
    d2 = cur[tid];
    int s = 0;
    for (int j = 0; j < tid; ++j) s += (cur[j] + 3) & ~3;
    st2 = s;
  }
  __syncthreads();
  if (tid < 100) {
    dinv[tid] = 1.0f / sqrtf((float)d2 + 1.0f);
    cur[tid] = st2;
    off[tid + 1] = st2 + ((d2 + 3) & ~3);
    if (tid == 0) off[0] = 0;
  }
  __syncthreads();
#pragma unroll
  for (int u = 0; u < 7; ++u)
    if (ed[u] >= 0) {
      int p = atomicAdd(&cur[ed[u]], 1);
      csr[p] = (unsigned short)(es[u] << 6);
    }
  __syncthreads();
  float* Ws = hl;                           // 4096 floats
  float* hl2 = hl + 4096;                   // 101 rows (row 100 = 0)
  float* hpost2 = hl + 4096 + 101 * 64;     // 100 rows
  if (tid < 100) {
    int pend = off[tid + 1];
    for (int p = cur[tid]; p < pend; ++p) csr[p] = (unsigned short)(100 * 64);
  }
  for (int i = tid; i < 4096; i += 1024) Ws[i] = W2[i];
  if (tid < 64) hl2[100 * 64 + tid] = 0.f;
  __syncthreads();

  // ---- gemm2: hl2 = dinv2 * (hp @ W2) ----
  {
    float acc[7];
#pragma unroll
    for (int p = 0; p < 7; ++p) acc[p] = 0.f;
    for (int kb = 0; kb < 64; kb += 4) {
      float w0  = Ws[(kb + 0) * 64 + lane];
      float w1  = Ws[(kb + 1) * 64 + lane];
      float w2v = Ws[(kb + 2) * 64 + lane];
      float w3v = Ws[(kb + 3) * 64 + lane];
#pragma unroll
      for (int p = 0; p < 7; ++p) {
        int n = wave + p * 16;
        if (n < 100) {
          float4 hv = *reinterpret_cast<const float4*>(&hp[n * 64 + kb]);
          acc[p] = fmaf(hv.x, w0, acc[p]);
          acc[p] = fmaf(hv.y, w1, acc[p]);
          acc[p] = fmaf(hv.z, w2v, acc[p]);
          acc[p] = fmaf(hv.w, w3v, acc[p]);
        }
      }
    }
#pragma unroll
    for (int p = 0; p < 7; ++p) {
      int n = wave + p * 16;
      if (n < 100) hl2[n * 64 + lane] = dinv[n] * acc[p];
    }
  }
  __syncthreads();

  // ---- gather2 + post + score ----
  {
    const float bc2 = b2[lane], pwc2 = pw2[lane];
#pragma unroll
    for (int it = 0; it < 7; ++it) {
      int n = wave + it * 16;
      if (n < 100) {
        float a0 = hl2[n * 64 + lane], a1 = 0.f;
        int e = off[n], end = off[n + 1];
        for (; e < end; e += 4) {
          uint2 pk = *reinterpret_cast<const uint2*>(&csr[e]);
          a0 += hl2[(pk.x & 0xFFFF) + lane];
          a1 += hl2[(pk.x >> 16) + lane];
          a0 += hl2[(pk.y & 0xFFFF) + lane];
          a1 += hl2[(pk.y >> 16) + lane];
        }
        float o = fmaxf(fmaf(a0 + a1, dinv[n], bc2), 0.f);
        hpost2[n * 64 + lane] = o;
        float sd = o * pwc2;
        sd += __shfl_xor(sd, 1);  sd += __shfl_xor(sd, 2);
        sd += __shfl_xor(sd, 4);  sd += __shfl_xor(sd, 8);
        sd += __shfl_xor(sd, 16); sd += __shfl_xor(sd, 32);
        if (lane == 0) sc[n] = sd;
      }
    }
  }
  __syncthreads();
  if (tid < 100) sc[tid] = tanhf(sc[tid] / nrm2_s);
  __syncthreads();

  // ---- rank2 ----
  if (tid < 50) {
    int i0 = tid * 2, i1 = i0 + 1;
    float s0 = sc[i0], s1 = sc[i1];
    int rk0 = 0, rk1 = 0;
    for (int j = 0; j < 100; ++j) {
      float sj = sc[j];
      rk0 += (sj > s0) || (sj == s0 && j < i0);
      rk1 += (sj > s1) || (sj == s1 && j < i1);
    }
    lmap[i0] = (rk0 < 25) ? rk0 : -1;
    if (rk0 < 25) sel[rk0] = i0;
    lmap[i1] = (rk1 < 25) ? rk1 : -1;
    if (rk1 < 25) sel[rk1] = i1;
  }
  __syncthreads();

  // ---- hp2 extract + remap + zero deg3 ----
  if (tid < 400) {
    int r = tid >> 4, c4 = (tid & 15) * 4;
    int n = sel[r];
    float s = sc[n];
    float4 vv = *reinterpret_cast<const float4*>(&hpost2[n * 64 + c4]);
    vv.x *= s; vv.y *= s; vv.z *= s; vv.w *= s;
    *reinterpret_cast<float4*>(&hp[r * 64 + c4]) = vv;
  }
#pragma unroll
  for (int u = 0; u < 7; ++u)
    if (ed[u] >= 0) {
      int a = lmap[es[u]], b = lmap[ed[u]];
      if ((a | b) >= 0) { es[u] = a; ed[u] = b; } else ed[u] = -1;
    }
  if (tid >= 512 && tid < 537) cur[tid - 512] = 0;
  __syncthreads();

  // ---- r2 sums + deg3 ----
  if (tid < 64) {
    float s = 0.f;
    for (int r = 0; r < 25; ++r) s += hp[r * 64 + tid];
    r2s[tid] = s;
  }
#pragma unroll
  for (int u = 0; u < 7; ++u)
    if (ed[u] >= 0) atomicAdd(&cur[ed[u]], 1);
  __syncthreads();

  // ---- scan3 ----
  int d3 = 0, st3 = 0;
  if (tid < 25) {
    d3 = cur[tid];
    int s = 0;
    for (int j = 0; j < tid; ++j) s += (cur[j] + 3) & ~3;
    st3 = s;
  }
  __syncthreads();
  if (tid < 25) {
    dinv[tid] = 1.0f / sqrtf((float)d3 + 1.0f);
    cur[tid] = st3;
    off[tid + 1] = st3 + ((d3 + 3) & ~3);
    if (tid == 0) off[0] = 0;
  }
  __syncthreads();
#pragma unroll
  for (int u = 0; u < 7; ++u)
    if (ed[u] >= 0) {
      int p = atomicAdd(&cur[ed[u]], 1);
      csr[p] = (unsigned short)(es[u] << 6);
    }
  __syncthreads();
  float* hl3 = hl + 4096;                   // 26 rows (row 25 = 0)
  if (tid < 25) {
    int pend = off[tid + 1];
    for (int p = cur[tid]; p < pend; ++p) csr[p] = (unsigned short)(25 * 64);
  }
  for (int i = tid; i < 4096; i += 1024) Ws[i] = W3[i];
  if (tid < 64) hl3[25 * 64 + tid] = 0.f;
  __syncthreads();

  // ---- gemm3 (P=2) ----
  {
    float a0c = 0.f, a1c = 0.f;
    const int n1 = wave + 16;
    for (int kb = 0; kb < 64; kb += 4) {
      float w0  = Ws[(kb + 0) * 64 + lane];
      float w1  = Ws[(kb + 1) * 64 + lane];
      float w2v = Ws[(kb + 2) * 64 + lane];
      float w3v = Ws[(kb + 3) * 64 + lane];
      {
        float4 hv = *reinterpret_cast<const float4*>(&hp[wave * 64 + kb]);
        a0c = fmaf(hv.x, w0, a0c);
        a0c = fmaf(hv.y, w1, a0c);
        a0c = fmaf(hv.z, w2v, a0c);
        a0c = fmaf(hv.w, w3v, a0c);
      }
      if (n1 < 25) {
        float4 hv = *reinterpret_cast<const float4*>(&hp[n1 * 64 + kb]);
        a1c = fmaf(hv.x, w0, a1c);
        a1c = fmaf(hv.y, w1, a1c);
        a1c = fmaf(hv.z, w2v, a1c);
        a1c = fmaf(hv.w, w3v, a1c);
      }
    }
    hl3[wave * 64 + lane] = dinv[wave] * a0c;
    if (n1 < 25) hl3[n1 * 64 + lane] = dinv[n1] * a1c;
  }
  __syncthreads();

  // ---- gather3 + r3 partials ----
  {
    const float bc3 = b3[lane];
    float part = 0.f;
#pragma unroll
    for (int it = 0; it < 2; ++it) {
      int n = wave + it * 16;
      if (n < 25) {
        float a0 = hl3[n * 64 + lane], a1 = 0.f;
        int e = off[n], end = off[n + 1];
        for (; e < end; e += 4) {
          uint2 pk = *reinterpret_cast<const uint2*>(&csr[e]);
          a0 += hl3[(pk.x & 0xFFFF) + lane];
          a1 += hl3[(pk.x >> 16) + lane];
          a0 += hl3[(pk.y & 0xFFFF) + lane];
          a1 += hl3[(pk.y >> 16) + lane];
        }
        part += fmaxf(fmaf(a0 + a1, dinv[n], bc3), 0.f);
      }
    }
    float* red = hl + 8192;
    red[wave * 64 + lane] = part;
  }
  __syncthreads();

  // ---- final linear ----
  if (tid < 64) {
    float* red = hl + 8192;
    float r3c = 0.f;
#pragma unroll
    for (int w = 0; w < 16; ++w) r3c += red[w * 64 + tid];
    float f1 = r2s[tid], f2 = r1s[tid];
    float p0 = r3c * Wl[tid * 2 + 0] + f1 * Wl[(64 + tid) * 2 + 0] + f2 * Wl[(128 + tid) * 2 + 0];
    float p1 = r3c * Wl[tid * 2 + 1] + f1 * Wl[(64 + tid) * 2 + 1] + f2 * Wl[(128 + tid) * 2 + 1];
#pragma unroll
    for (int o = 32; o; o >>= 1) {
      p0 += __shfl_xor(p0, o);
      p1 += __shfl_xor(p1, o);
    }
    if (tid == 0) {
      out[g * 2 + 0] = p0 + bl[0];
      out[g * 2 + 1] = p1 + bl[1];
    }
  }
}

// ---------------------------------------------------------------------------
extern "C" void kernel_launch(void* const* d_in, const int* in_sizes, int n_in,
                              void* d_out, int out_size, void* d_ws, size_t ws_size,
                              hipStream_t stream) {
  const float* x   = (const float*)d_in[0];
  const int*   src = (const int*)d_in[1];
  const int*   dst = (const int*)d_in[2];
  const float* W1  = (const float*)d_in[4];
  const float* b1  = (const float*)d_in[5];
  const float* W2  = (const float*)d_in[6];
  const float* b2  = (const float*)d_in[7];
  const float* W3  = (const float*)d_in[8];
  const float* b3  = (const float*)d_in[9];
  const float* pw1 = (const float*)d_in[10];
  const float* pw2 = (const float*)d_in[11];
  const float* Wl  = (const float*)d_in[12];
  const float* bl  = (const float*)d_in[13];
  float* out = (float*)d_out;

  float* h1 = (float*)d_ws;   // 102400 x 64 floats

  gemm64<128><<<102400 / 64, 256, 0, stream>>>(x, W1, h1);
  mega<<<BGR, 1024, 0, stream>>>(h1, src, dst, b1, pw1, W2, b2, pw2,
                                 W3, b3, Wl, bl, out);
}

// Round 9
// 130.826 us; speedup vs baseline: 1.6584x; 1.0554x over previous
//
#include <hip/hip_runtime.h>
#include <math.h>

#define BGR  256      // graphs
#define NN   400      // nodes per graph (stage 1)
#define EPG  6400     // edges per graph

// ---------------------------------------------------------------------------
// GEMM: H = X @ W per graph-tile, XCD-aligned: grid (256 graphs, 7 tiles);
// linear block id = g + 256*t -> XCD = g%8, matching mega's block g. Tile
// t<6: 64 rows, t==6: 16 rows (400 = 6*64+16).
// ---------------------------------------------------------------------------
template<int K>
__global__ __launch_bounds__(256) void gemm64x(const float* __restrict__ X,
                                               const float* __restrict__ W,
                                               float* __restrict__ H) {
  __shared__ float xs[64][K + 4];
  const int g = blockIdx.x, t = blockIdx.y;
  const int nrows = (t == 6) ? 16 : 64;
  const size_t rbase = (size_t)g * NN + t * 64;
  for (int i = threadIdx.x; i < 64 * (K / 4); i += 256) {
    int m = i / (K / 4), q = i % (K / 4);
    if (m < nrows)
      *reinterpret_cast<float4*>(&xs[m][q * 4]) =
          *reinterpret_cast<const float4*>(X + (rbase + m) * K + q * 4);
  }
  __syncthreads();
  const int c = threadIdx.x & 63;
  const int mg = (threadIdx.x >> 6) * 16;
  if (mg < nrows) {
    float acc[16];
#pragma unroll
    for (int i = 0; i < 16; ++i) acc[i] = 0.f;
    for (int k = 0; k < K; k += 4) {
      float w0 = W[(k + 0) * 64 + c];
      float w1 = W[(k + 1) * 64 + c];
      float w2 = W[(k + 2) * 64 + c];
      float w3 = W[(k + 3) * 64 + c];
#pragma unroll
      for (int i = 0; i < 16; ++i) {
        float4 xv = *reinterpret_cast<const float4*>(&xs[mg + i][k]);
        float a = acc[i];
        a = fmaf(xv.x, w0, a);
        a = fmaf(xv.y, w1, a);
        a = fmaf(xv.z, w2, a);
        a = fmaf(xv.w, w3, a);
        acc[i] = a;
      }
    }
#pragma unroll
    for (int i = 0; i < 16; ++i)
      H[(rbase + mg + i) * 64 + c] = acc[i];
  }
}

// ---------------------------------------------------------------------------
// Mega-kernel: stages 1+2+3 fused, one block (1024 thr) per graph.
// gather1: dual-stream b64 (half-waves process even/odd edges, float2/lane,
// shfl_xor(32) combine); score+tanh folded into gather epilogue.
// ---------------------------------------------------------------------------
__global__ __launch_bounds__(1024, 4) void mega(
    const float* __restrict__ h1,
    const int* __restrict__ src, const int* __restrict__ dst,
    const float* __restrict__ b1, const float* __restrict__ pw1,
    const float* __restrict__ W2, const float* __restrict__ b2,
    const float* __restrict__ pw2,
    const float* __restrict__ W3, const float* __restrict__ b3,
    const float* __restrict__ Wl, const float* __restrict__ bl,
    float* __restrict__ out) {
  __shared__ float hl[401 * 64];                       // 102,656 B (row 400 = 0)
  __shared__ __align__(16) unsigned short csr[9216];   // 18,432 B
  __shared__ int   off[NN + 1];
  __shared__ int   cur[NN];
  __shared__ float dinv[NN];
  __shared__ float sc[NN];
  __shared__ int   sel[100];
  __shared__ int   lmap[NN];
  __shared__ float hp[100 * 64];                       // 25,600 B
  __shared__ float r1s[64], r2s[64];
  __shared__ int   wpart[8];
  __shared__ float nrm1_s, nrm2_s;

  const int g = blockIdx.x, tid = threadIdx.x;
  const int lane = tid & 63, wave = tid >> 6;
  const int e0 = g * EPG;
  const size_t hbase = (size_t)g * NN * 64;

  // ---- init: zero deg (cur), zero row 400, pw norms ----
  for (int i = tid; i < NN; i += 1024) cur[i] = 0;
  if (tid < 64) hl[400 * 64 + tid] = 0.f;
  if (wave == 14) {
    float p = pw1[lane], t = p * p;
#pragma unroll
    for (int o = 32; o; o >>= 1) t += __shfl_xor(t, o);
    if (lane == 0) nrm1_s = sqrtf(t);
  }
  if (wave == 15) {
    float p = pw2[lane], t = p * p;
#pragma unroll
    for (int o = 32; o; o >>= 1) t += __shfl_xor(t, o);
    if (lane == 0) nrm2_s = sqrtf(t);
  }
  __syncthreads();

  // ---- edges to regs + h1 prefetch + degree ----
  int es[7], ed[7];
#pragma unroll
  for (int u = 0; u < 7; ++u) {
    int e = tid + u * 1024;
    if (e < EPG) { es[u] = src[e0 + e] - g * NN; ed[u] = dst[e0 + e] - g * NN; }
    else         { es[u] = 0; ed[u] = -1; }
  }
  float4 hreg[7];
#pragma unroll
  for (int u = 0; u < 7; ++u) {
    int i = tid + u * 1024;
    if (i < NN * 16)
      hreg[u] = *reinterpret_cast<const float4*>(&h1[hbase + (size_t)i * 4]);
  }
#pragma unroll
  for (int u = 0; u < 7; ++u)
    if (ed[u] >= 0) atomicAdd(&cur[ed[u]], 1);
  __syncthreads();

  // ---- scan of padded degrees (x8); dinv ----
  int vincl = 0, myp = 0;
  if (tid < NN) {
    int d = cur[tid];
    dinv[tid] = 1.0f / sqrtf((float)d + 1.0f);
    myp = (d + 7) & ~7;
    vincl = myp;
#pragma unroll
    for (int o = 1; o < 64; o <<= 1) {
      int t = __shfl_up(vincl, o);
      if ((tid & 63) >= o) vincl += t;
    }
    if ((tid & 63) == 63 || tid == NN - 1) wpart[tid >> 6] = vincl;
  }
  __syncthreads();
  if (tid < NN) {
    int base = 0, w = tid >> 6;
    for (int j = 0; j < w; ++j) base += wpart[j];
    int incl = base + vincl;
    off[tid + 1] = incl;
    cur[tid] = incl - myp;
    if (tid == 0) off[0] = 0;
  }
  __syncthreads();

  // ---- stage hl (dinv-scaled) + csr fill ----
#pragma unroll
  for (int u = 0; u < 7; ++u) {
    int i = tid + u * 1024;
    if (i < NN * 16) {
      int n = i >> 4;
      float dn = dinv[n];
      float4 vv = hreg[u];
      vv.x *= dn; vv.y *= dn; vv.z *= dn; vv.w *= dn;
      *reinterpret_cast<float4*>(&hl[i * 4]) = vv;
    }
  }
#pragma unroll
  for (int u = 0; u < 7; ++u)
    if (ed[u] >= 0) {
      int p = atomicAdd(&cur[ed[u]], 1);
      csr[p] = (unsigned short)(es[u] << 6);
    }
  __syncthreads();
  if (tid < NN) {
    int pend = off[tid + 1];
    for (int p = cur[tid]; p < pend; ++p) csr[p] = (unsigned short)(400 * 64);
  }
  __syncthreads();

  // ---- gather1: dual-stream b64, wave-per-node; score+tanh fused ----
  {
    const int half = lane >> 5;
    const int cp = (lane & 31) * 2;
    const float2 bb = *reinterpret_cast<const float2*>(&b1[cp]);
    const float2 pv = *reinterpret_cast<const float2*>(&pw1[cp]);
    float2 outv[25];
#pragma unroll
    for (int it = 0; it < 25; ++it) {
      int n = it * 16 + wave;
      int e = off[n], end = off[n + 1];
      float ax = 0.f, ay = 0.f, bx = 0.f, by = 0.f;
      for (; e < end; e += 8) {
        uint4 pk = *reinterpret_cast<const uint4*>(&csr[e]);
        unsigned q0 = half ? (pk.x >> 16) : (pk.x & 0xFFFF);
        unsigned q1 = half ? (pk.y >> 16) : (pk.y & 0xFFFF);
        unsigned q2 = half ? (pk.z >> 16) : (pk.z & 0xFFFF);
        unsigned q3 = half ? (pk.w >> 16) : (pk.w & 0xFFFF);
        float2 v0 = *reinterpret_cast<const float2*>(&hl[q0 + cp]);
        float2 v1 = *reinterpret_cast<const float2*>(&hl[q1 + cp]);
        float2 v2 = *reinterpret_cast<const float2*>(&hl[q2 + cp]);
        float2 v3 = *reinterpret_cast<const float2*>(&hl[q3 + cp]);
        ax += v0.x; ay += v0.y;
        bx += v1.x; by += v1.y;
        ax += v2.x; ay += v2.y;
        bx += v3.x; by += v3.y;
      }
      float sx = ax + bx, sy = ay + by;
      sx += __shfl_xor(sx, 32);
      sy += __shfl_xor(sy, 32);
      float2 self = *reinterpret_cast<const float2*>(&hl[(n << 6) + cp]);
      float dn = dinv[n];
      float ox = fmaxf(fmaf(sx + self.x, dn, bb.x), 0.f);
      float oy = fmaxf(fmaf(sy + self.y, dn, bb.y), 0.f);
      outv[it] = make_float2(ox, oy);
      float sd = ox * pv.x + oy * pv.y;
      sd += __shfl_xor(sd, 1);
      sd += __shfl_xor(sd, 2);
      sd += __shfl_xor(sd, 4);
      sd += __shfl_xor(sd, 8);
      sd += __shfl_xor(sd, 16);
      if (lane == 0) sc[n] = tanhf(sd / nrm1_s);
    }
    __syncthreads();   // all reads of hl done
#pragma unroll
    for (int it = 0; it < 25; ++it) {
      int n = it * 16 + wave;
      if (half == 0)
        *reinterpret_cast<float2*>(&hl[(n << 6) + cp]) = outv[it];
    }
  }
  __syncthreads();

  // ---- rank1 (stable, 2 nodes/thread) ----
  if (tid < 200) {
    int i0 = tid * 2, i1 = i0 + 1;
    float s0 = sc[i0], s1 = sc[i1];
    int rk0 = 0, rk1 = 0;
    for (int j = 0; j < NN; ++j) {
      float sj = sc[j];
      rk0 += (sj > s0) || (sj == s0 && j < i0);
      rk1 += (sj > s1) || (sj == s1 && j < i1);
    }
    lmap[i0] = (rk0 < 100) ? rk0 : -1;
    if (rk0 < 100) sel[rk0] = i0;
    lmap[i1] = (rk1 < 100) ? rk1 : -1;
    if (rk1 < 100) sel[rk1] = i1;
  }
  __syncthreads();

  // ---- hp extract (scaled) + edge remap + zero deg2 ----
  {
    int r = tid >> 4, c4 = (tid & 15) * 4;
    int n = sel[r];
    float s = sc[n];
    float4 vv = *reinterpret_cast<const float4*>(&hl[(n << 6) + c4]);
    vv.x *= s; vv.y *= s; vv.z *= s; vv.w *= s;
    *reinterpret_cast<float4*>(&hp[r * 64 + c4]) = vv;
    if (tid < 576) {
      int r2 = r + 64;
      int n2 = sel[r2];
      float s2 = sc[n2];
      float4 v2 = *reinterpret_cast<const float4*>(&hl[(n2 << 6) + c4]);
      v2.x *= s2; v2.y *= s2; v2.z *= s2; v2.w *= s2;
      *reinterpret_cast<float4*>(&hp[r2 * 64 + c4]) = v2;
    }
  }
#pragma unroll
  for (int u = 0; u < 7; ++u)
    if (ed[u] >= 0) {
      int a = lmap[es[u]], b = lmap[ed[u]];
      if ((a | b) >= 0) { es[u] = a; ed[u] = b; } else ed[u] = -1;
    }
  if (tid >= 512 && tid < 612) cur[tid - 512] = 0;
  __syncthreads();

  // ---- r1 sums + deg2 ----
  if (tid < 64) {
    float s = 0.f;
    for (int r = 0; r < 100; ++r) s += hp[r * 64 + tid];
    r1s[tid] = s;
  }
#pragma unroll
  for (int u = 0; u < 7; ++u)
    if (ed[u] >= 0) atomicAdd(&cur[ed[u]], 1);
  __syncthreads();

  // ---- scan2 (shfl, pad x4) ----
  {
    int d2 = 0, p2 = 0, v2s = 0;
    if (tid < 100) {
      d2 = cur[tid];
      p2 = (d2 + 3) & ~3;
      v2s = p2;
    }
#pragma unroll
    for (int o = 1; o < 64; o <<= 1) {
      int t = __shfl_up(v2s, o);
      if ((tid & 63) >= o) v2s += t;
    }
    if (tid < 100 && ((tid & 63) == 63 || tid == 99)) wpart[tid >> 6] = v2s;
    __syncthreads();
    if (tid < 100) {
      int base = (tid >= 64) ? wpart[0] : 0;
      int incl = base + v2s;
      dinv[tid] = 1.0f / sqrtf((float)d2 + 1.0f);
      off[tid + 1] = incl;
      cur[tid] = incl - p2;
      if (tid == 0) off[0] = 0;
    }
  }
  __syncthreads();
#pragma unroll
  for (int u = 0; u < 7; ++u)
    if (ed[u] >= 0) {
      int p = atomicAdd(&cur[ed[u]], 1);
      csr[p] = (unsigned short)(es[u] << 6);
    }
  __syncthreads();
  float* Ws = hl;                           // 4096 floats
  float* hl2 = hl + 4096;                   // 101 rows (row 100 = 0)
  float* hpost2 = hl + 4096 + 101 * 64;     // 100 rows
  if (tid < 100) {
    int pend = off[tid + 1];
    for (int p = cur[tid]; p < pend; ++p) csr[p] = (unsigned short)(100 * 64);
  }
  for (int i = tid; i < 4096; i += 1024) Ws[i] = W2[i];
  if (tid < 64) hl2[100 * 64 + tid] = 0.f;
  __syncthreads();

  // ---- gemm2: hl2 = dinv2 * (hp @ W2) ----
  {
    float acc[7];
#pragma unroll
    for (int p = 0; p < 7; ++p) acc[p] = 0.f;
    for (int kb = 0; kb < 64; kb += 4) {
      float w0  = Ws[(kb + 0) * 64 + lane];
      float w1  = Ws[(kb + 1) * 64 + lane];
      float w2v = Ws[(kb + 2) * 64 + lane];
      float w3v = Ws[(kb + 3) * 64 + lane];
#pragma unroll
      for (int p = 0; p < 7; ++p) {
        int n = wave + p * 16;
        if (n < 100) {
          float4 hv = *reinterpret_cast<const float4*>(&hp[n * 64 + kb]);
          acc[p] = fmaf(hv.x, w0, acc[p]);
          acc[p] = fmaf(hv.y, w1, acc[p]);
          acc[p] = fmaf(hv.z, w2v, acc[p]);
          acc[p] = fmaf(hv.w, w3v, acc[p]);
        }
      }
    }
#pragma unroll
    for (int p = 0; p < 7; ++p) {
      int n = wave + p * 16;
      if (n < 100) hl2[n * 64 + lane] = dinv[n] * acc[p];
    }
  }
  __syncthreads();

  // ---- gather2 + post + score ----
  {
    const float bc2 = b2[lane], pwc2 = pw2[lane];
#pragma unroll
    for (int it = 0; it < 7; ++it) {
      int n = wave + it * 16;
      if (n < 100) {
        float a0 = hl2[n * 64 + lane], a1 = 0.f;
        int e = off[n], end = off[n + 1];
        for (; e < end; e += 4) {
          uint2 pk = *reinterpret_cast<const uint2*>(&csr[e]);
          a0 += hl2[(pk.x & 0xFFFF) + lane];
          a1 += hl2[(pk.x >> 16) + lane];
          a0 += hl2[(pk.y & 0xFFFF) + lane];
          a1 += hl2[(pk.y >> 16) + lane];
        }
        float o = fmaxf(fmaf(a0 + a1, dinv[n], bc2), 0.f);
        hpost2[n * 64 + lane] = o;
        float sd = o * pwc2;
        sd += __shfl_xor(sd, 1);  sd += __shfl_xor(sd, 2);
        sd += __shfl_xor(sd, 4);  sd += __shfl_xor(sd, 8);
        sd += __shfl_xor(sd, 16); sd += __shfl_xor(sd, 32);
        if (lane == 0) sc[n] = sd;
      }
    }
  }
  __syncthreads();
  if (tid < 100) sc[tid] = tanhf(sc[tid] / nrm2_s);
  __syncthreads();

  // ---- rank2 ----
  if (tid < 50) {
    int i0 = tid * 2, i1 = i0 + 1;
    float s0 = sc[i0], s1 = sc[i1];
    int rk0 = 0, rk1 = 0;
    for (int j = 0; j < 100; ++j) {
      float sj = sc[j];
      rk0 += (sj > s0) || (sj == s0 && j < i0);
      rk1 += (sj > s1) || (sj == s1 && j < i1);
    }
    lmap[i0] = (rk0 < 25) ? rk0 : -1;
    if (rk0 < 25) sel[rk0] = i0;
    lmap[i1] = (rk1 < 25) ? rk1 : -1;
    if (rk1 < 25) sel[rk1] = i1;
  }
  __syncthreads();

  // ---- hp2 extract + remap + zero deg3 ----
  if (tid < 400) {
    int r = tid >> 4, c4 = (tid & 15) * 4;
    int n = sel[r];
    float s = sc[n];
    float4 vv = *reinterpret_cast<const float4*>(&hpost2[n * 64 + c4]);
    vv.x *= s; vv.y *= s; vv.z *= s; vv.w *= s;
    *reinterpret_cast<float4*>(&hp[r * 64 + c4]) = vv;
  }
#pragma unroll
  for (int u = 0; u < 7; ++u)
    if (ed[u] >= 0) {
      int a = lmap[es[u]], b = lmap[ed[u]];
      if ((a | b) >= 0) { es[u] = a; ed[u] = b; } else ed[u] = -1;
    }
  if (tid >= 512 && tid < 537) cur[tid - 512] = 0;
  __syncthreads();

  // ---- r2 sums + deg3 ----
  if (tid < 64) {
    float s = 0.f;
    for (int r = 0; r < 25; ++r) s += hp[r * 64 + tid];
    r2s[tid] = s;
  }
#pragma unroll
  for (int u = 0; u < 7; ++u)
    if (ed[u] >= 0) atomicAdd(&cur[ed[u]], 1);
  __syncthreads();

  // ---- scan3 (single-wave shfl, pad x4) ----
  {
    int d3 = 0, p3 = 0, v3s = 0;
    if (tid < 25) {
      d3 = cur[tid];
      p3 = (d3 + 3) & ~3;
      v3s = p3;
    }
    if (tid < 64) {
#pragma unroll
      for (int o = 1; o < 32; o <<= 1) {
        int t = __shfl_up(v3s, o);
        if (lane >= o) v3s += t;
      }
    }
    __syncthreads();
    if (tid < 25) {
      dinv[tid] = 1.0f / sqrtf((float)d3 + 1.0f);
      off[tid + 1] = v3s;
      cur[tid] = v3s - p3;
      if (tid == 0) off[0] = 0;
    }
  }
  __syncthreads();
#pragma unroll
  for (int u = 0; u < 7; ++u)
    if (ed[u] >= 0) {
      int p = atomicAdd(&cur[ed[u]], 1);
      csr[p] = (unsigned short)(es[u] << 6);
    }
  __syncthreads();
  float* hl3 = hl + 4096;                   // 26 rows (row 25 = 0)
  if (tid < 25) {
    int pend = off[tid + 1];
    for (int p = cur[tid]; p < pend; ++p) csr[p] = (unsigned short)(25 * 64);
  }
  for (int i = tid; i < 4096; i += 1024) Ws[i] = W3[i];
  if (tid < 64) hl3[25 * 64 + tid] = 0.f;
  __syncthreads();

  // ---- gemm3 (P=2) ----
  {
    float a0c = 0.f, a1c = 0.f;
    const int n1 = wave + 16;
    for (int kb = 0; kb < 64; kb += 4) {
      float w0  = Ws[(kb + 0) * 64 + lane];
      float w1  = Ws[(kb + 1) * 64 + lane];
      float w2v = Ws[(kb + 2) * 64 + lane];
      float w3v = Ws[(kb + 3) * 64 + lane];
      {
        float4 hv = *reinterpret_cast<const float4*>(&hp[wave * 64 + kb]);
        a0c = fmaf(hv.x, w0, a0c);
        a0c = fmaf(hv.y, w1, a0c);
        a0c = fmaf(hv.z, w2v, a0c);
        a0c = fmaf(hv.w, w3v, a0c);
      }
      if (n1 < 25) {
        float4 hv = *reinterpret_cast<const float4*>(&hp[n1 * 64 + kb]);
        a1c = fmaf(hv.x, w0, a1c);
        a1c = fmaf(hv.y, w1, a1c);
        a1c = fmaf(hv.z, w2v, a1c);
        a1c = fmaf(hv.w, w3v, a1c);
      }
    }
    hl3[wave * 64 + lane] = dinv[wave] * a0c;
    if (n1 < 25) hl3[n1 * 64 + lane] = dinv[n1] * a1c;
  }
  __syncthreads();

  // ---- gather3 + r3 partials ----
  {
    const float bc3 = b3[lane];
    float part = 0.f;
#pragma unroll
    for (int it = 0; it < 2; ++it) {
      int n = wave + it * 16;
      if (n < 25) {
        float a0 = hl3[n * 64 + lane], a1 = 0.f;
        int e = off[n], end = off[n + 1];
        for (; e < end; e += 4) {
          uint2 pk = *reinterpret_cast<const uint2*>(&csr[e]);
          a0 += hl3[(pk.x & 0xFFFF) + lane];
          a1 += hl3[(pk.x >> 16) + lane];
          a0 += hl3[(pk.y & 0xFFFF) + lane];
          a1 += hl3[(pk.y >> 16) + lane];
        }
        part += fmaxf(fmaf(a0 + a1, dinv[n], bc3), 0.f);
      }
    }
    float* red = hl + 8192;
    red[wave * 64 + lane] = part;
  }
  __syncthreads();

  // ---- final linear ----
  if (tid < 64) {
    float* red = hl + 8192;
    float r3c = 0.f;
#pragma unroll
    for (int w = 0; w < 16; ++w) r3c += red[w * 64 + tid];
    float f1 = r2s[tid], f2 = r1s[tid];
    float p0 = r3c * Wl[tid * 2 + 0] + f1 * Wl[(64 + tid) * 2 + 0] + f2 * Wl[(128 + tid) * 2 + 0];
    float p1 = r3c * Wl[tid * 2 + 1] + f1 * Wl[(64 + tid) * 2 + 1] + f2 * Wl[(128 + tid) * 2 + 1];
#pragma unroll
    for (int o = 32; o; o >>= 1) {
      p0 += __shfl_xor(p0, o);
      p1 += __shfl_xor(p1, o);
    }
    if (tid == 0) {
      out[g * 2 + 0] = p0 + bl[0];
      out[g * 2 + 1] = p1 + bl[1];
    }
  }
}

// ---------------------------------------------------------------------------
extern "C" void kernel_launch(void* const* d_in, const int* in_sizes, int n_in,
                              void* d_out, int out_size, void* d_ws, size_t ws_size,
                              hipStream_t stream) {
  const float* x   = (const float*)d_in[0];
  const int*   src = (const int*)d_in[1];
  const int*   dst = (const int*)d_in[2];
  const float* W1  = (const float*)d_in[4];
  const float* b1  = (const float*)d_in[5];
  const float* W2  = (const float*)d_in[6];
  const float* b2  = (const float*)d_in[7];
  const float* W3  = (const float*)d_in[8];
  const float* b3  = (const float*)d_in[9];
  const float* pw1 = (const float*)d_in[10];
  const float* pw2 = (const float*)d_in[11];
  const float* Wl  = (const float*)d_in[12];
  const float* bl  = (const float*)d_in[13];
  float* out = (float*)d_out;

  float* h1 = (float*)d_ws;   // 102400 x 64 floats

  gemm64x<128><<<dim3(BGR, 7), 256, 0, stream>>>(x, W1, h1);
  mega<<<BGR, 1024, 0, stream>>>(h1, src, dst, b1, pw1, W2, b2, pw2,
                                 W3, b3, Wl, bl, out);
}

// Round 10
// 128.626 us; speedup vs baseline: 1.6867x; 1.0171x over previous
//
#include <hip/hip_runtime.h>
#include <math.h>

#define BGR  256      // graphs
#define NN   400      // nodes per graph (stage 1)
#define EPG  6400     // edges per graph

// ---------------------------------------------------------------------------
// GEMM: H = X @ W per graph-tile, XCD-aligned: grid (256 graphs, 7 tiles);
// linear block id = g + 256*t -> XCD = g%8, matching mega's block g.
// ---------------------------------------------------------------------------
template<int K>
__global__ __launch_bounds__(256) void gemm64x(const float* __restrict__ X,
                                               const float* __restrict__ W,
                                               float* __restrict__ H) {
  __shared__ float xs[64][K + 4];
  const int g = blockIdx.x, t = blockIdx.y;
  const int nrows = (t == 6) ? 16 : 64;
  const size_t rbase = (size_t)g * NN + t * 64;
  for (int i = threadIdx.x; i < 64 * (K / 4); i += 256) {
    int m = i / (K / 4), q = i % (K / 4);
    if (m < nrows)
      *reinterpret_cast<float4*>(&xs[m][q * 4]) =
          *reinterpret_cast<const float4*>(X + (rbase + m) * K + q * 4);
  }
  __syncthreads();
  const int c = threadIdx.x & 63;
  const int mg = (threadIdx.x >> 6) * 16;
  if (mg < nrows) {
    float acc[16];
#pragma unroll
    for (int i = 0; i < 16; ++i) acc[i] = 0.f;
    for (int k = 0; k < K; k += 4) {
      float w0 = W[(k + 0) * 64 + c];
      float w1 = W[(k + 1) * 64 + c];
      float w2 = W[(k + 2) * 64 + c];
      float w3 = W[(k + 3) * 64 + c];
#pragma unroll
      for (int i = 0; i < 16; ++i) {
        float4 xv = *reinterpret_cast<const float4*>(&xs[mg + i][k]);
        float a = acc[i];
        a = fmaf(xv.x, w0, a);
        a = fmaf(xv.y, w1, a);
        a = fmaf(xv.z, w2, a);
        a = fmaf(xv.w, w3, a);
        acc[i] = a;
      }
    }
#pragma unroll
    for (int i = 0; i < 16; ++i)
      H[(rbase + mg + i) * 64 + c] = acc[i];
  }
}

// ---------------------------------------------------------------------------
// Mega-kernel: stages 1+2+3 fused, one block (1024 thr) per graph.
// gather1: wave-per-node, lane=channel, b32 full-row reads (2-way bank
// aliasing = free); uint4 CSR broadcasts; score+tanh fused in epilogue.
// Rank phases use float4 broadcast reads.
// ---------------------------------------------------------------------------
__global__ __launch_bounds__(1024, 4) void mega(
    const float* __restrict__ h1,
    const int* __restrict__ src, const int* __restrict__ dst,
    const float* __restrict__ b1, const float* __restrict__ pw1,
    const float* __restrict__ W2, const float* __restrict__ b2,
    const float* __restrict__ pw2,
    const float* __restrict__ W3, const float* __restrict__ b3,
    const float* __restrict__ Wl, const float* __restrict__ bl,
    float* __restrict__ out) {
  __shared__ float hl[401 * 64];                       // 102,656 B (row 400 = 0)
  __shared__ __align__(16) unsigned short csr[9216];   // 18,432 B
  __shared__ int   off[NN + 1];
  __shared__ int   cur[NN];
  __shared__ float dinv[NN];
  __shared__ __align__(16) float sc[NN];
  __shared__ int   sel[100];
  __shared__ int   lmap[NN];
  __shared__ float hp[100 * 64];                       // 25,600 B
  __shared__ float r1s[64], r2s[64];
  __shared__ int   wpart[8];
  __shared__ float nrm1_s, nrm2_s;

  const int g = blockIdx.x, tid = threadIdx.x;
  const int lane = tid & 63, wave = tid >> 6;
  const int e0 = g * EPG;
  const size_t hbase = (size_t)g * NN * 64;

  // ---- init: zero deg (cur), zero row 400, pw norms ----
  for (int i = tid; i < NN; i += 1024) cur[i] = 0;
  if (tid < 64) hl[400 * 64 + tid] = 0.f;
  if (wave == 14) {
    float p = pw1[lane], t = p * p;
#pragma unroll
    for (int o = 32; o; o >>= 1) t += __shfl_xor(t, o);
    if (lane == 0) nrm1_s = sqrtf(t);
  }
  if (wave == 15) {
    float p = pw2[lane], t = p * p;
#pragma unroll
    for (int o = 32; o; o >>= 1) t += __shfl_xor(t, o);
    if (lane == 0) nrm2_s = sqrtf(t);
  }
  __syncthreads();

  // ---- edges to regs + h1 prefetch + degree ----
  int es[7], ed[7];
#pragma unroll
  for (int u = 0; u < 7; ++u) {
    int e = tid + u * 1024;
    if (e < EPG) { es[u] = src[e0 + e] - g * NN; ed[u] = dst[e0 + e] - g * NN; }
    else         { es[u] = 0; ed[u] = -1; }
  }
  float4 hreg[7];
#pragma unroll
  for (int u = 0; u < 7; ++u) {
    int i = tid + u * 1024;
    if (i < NN * 16)
      hreg[u] = *reinterpret_cast<const float4*>(&h1[hbase + (size_t)i * 4]);
  }
#pragma unroll
  for (int u = 0; u < 7; ++u)
    if (ed[u] >= 0) atomicAdd(&cur[ed[u]], 1);
  __syncthreads();

  // ---- scan of padded degrees (x8); dinv ----
  int vincl = 0, myp = 0;
  if (tid < NN) {
    int d = cur[tid];
    dinv[tid] = 1.0f / sqrtf((float)d + 1.0f);
    myp = (d + 7) & ~7;
    vincl = myp;
#pragma unroll
    for (int o = 1; o < 64; o <<= 1) {
      int t = __shfl_up(vincl, o);
      if ((tid & 63) >= o) vincl += t;
    }
    if ((tid & 63) == 63 || tid == NN - 1) wpart[tid >> 6] = vincl;
  }
  __syncthreads();
  if (tid < NN) {
    int base = 0, w = tid >> 6;
    for (int j = 0; j < w; ++j) base += wpart[j];
    int incl = base + vincl;
    off[tid + 1] = incl;
    cur[tid] = incl - myp;
    if (tid == 0) off[0] = 0;
  }
  __syncthreads();

  // ---- stage hl (dinv-scaled) + csr fill ----
#pragma unroll
  for (int u = 0; u < 7; ++u) {
    int i = tid + u * 1024;
    if (i < NN * 16) {
      int n = i >> 4;
      float dn = dinv[n];
      float4 vv = hreg[u];
      vv.x *= dn; vv.y *= dn; vv.z *= dn; vv.w *= dn;
      *reinterpret_cast<float4*>(&hl[i * 4]) = vv;
    }
  }
#pragma unroll
  for (int u = 0; u < 7; ++u)
    if (ed[u] >= 0) {
      int p = atomicAdd(&cur[ed[u]], 1);
      csr[p] = (unsigned short)(es[u] << 6);
    }
  __syncthreads();
  if (tid < NN) {
    int pend = off[tid + 1];
    for (int p = cur[tid]; p < pend; ++p) csr[p] = (unsigned short)(400 * 64);
  }
  __syncthreads();

  // ---- gather1: wave-per-node, b32 rows; score+tanh fused ----
  {
    const float bc1 = b1[lane], pwc1 = pw1[lane];
    float outv[25];
#pragma unroll
    for (int it = 0; it < 25; ++it) {
      int n = it * 16 + wave;
      int e = off[n], end = off[n + 1];
      float a0 = hl[(n << 6) + lane], a1 = 0.f, a2 = 0.f, a3 = 0.f;
      for (; e < end; e += 8) {
        uint4 pk = *reinterpret_cast<const uint4*>(&csr[e]);
        a0 += hl[(pk.x & 0xFFFF) + lane];
        a1 += hl[(pk.x >> 16) + lane];
        a2 += hl[(pk.y & 0xFFFF) + lane];
        a3 += hl[(pk.y >> 16) + lane];
        a0 += hl[(pk.z & 0xFFFF) + lane];
        a1 += hl[(pk.z >> 16) + lane];
        a2 += hl[(pk.w & 0xFFFF) + lane];
        a3 += hl[(pk.w >> 16) + lane];
      }
      float o = fmaxf(fmaf((a0 + a1) + (a2 + a3), dinv[n], bc1), 0.f);
      outv[it] = o;
      float sd = o * pwc1;
      sd += __shfl_xor(sd, 1);
      sd += __shfl_xor(sd, 2);
      sd += __shfl_xor(sd, 4);
      sd += __shfl_xor(sd, 8);
      sd += __shfl_xor(sd, 16);
      sd += __shfl_xor(sd, 32);
      if (lane == 0) sc[n] = tanhf(sd / nrm1_s);
    }
    __syncthreads();   // all reads of hl done
#pragma unroll
    for (int it = 0; it < 25; ++it)
      hl[((it * 16 + wave) << 6) + lane] = outv[it];
  }
  __syncthreads();

  // ---- rank1 (stable, 2 nodes/thread, float4 broadcast) ----
  if (tid < 200) {
    int i0 = tid * 2, i1 = i0 + 1;
    float s0 = sc[i0], s1 = sc[i1];
    int rk0 = 0, rk1 = 0;
    for (int j4 = 0; j4 < 100; ++j4) {
      float4 sv = *reinterpret_cast<const float4*>(&sc[j4 * 4]);
      int jb = j4 * 4;
      rk0 += (sv.x > s0) || (sv.x == s0 && jb     < i0);
      rk0 += (sv.y > s0) || (sv.y == s0 && jb + 1 < i0);
      rk0 += (sv.z > s0) || (sv.z == s0 && jb + 2 < i0);
      rk0 += (sv.w > s0) || (sv.w == s0 && jb + 3 < i0);
      rk1 += (sv.x > s1) || (sv.x == s1 && jb     < i1);
      rk1 += (sv.y > s1) || (sv.y == s1 && jb + 1 < i1);
      rk1 += (sv.z > s1) || (sv.z == s1 && jb + 2 < i1);
      rk1 += (sv.w > s1) || (sv.w == s1 && jb + 3 < i1);
    }
    lmap[i0] = (rk0 < 100) ? rk0 : -1;
    if (rk0 < 100) sel[rk0] = i0;
    lmap[i1] = (rk1 < 100) ? rk1 : -1;
    if (rk1 < 100) sel[rk1] = i1;
  }
  __syncthreads();

  // ---- hp extract (scaled) + edge remap + zero deg2 ----
  {
    int r = tid >> 4, c4 = (tid & 15) * 4;
    int n = sel[r];
    float s = sc[n];
    float4 vv = *reinterpret_cast<const float4*>(&hl[(n << 6) + c4]);
    vv.x *= s; vv.y *= s; vv.z *= s; vv.w *= s;
    *reinterpret_cast<float4*>(&hp[r * 64 + c4]) = vv;
    if (tid < 576) {
      int r2 = r + 64;
      int n2 = sel[r2];
      float s2 = sc[n2];
      float4 v2 = *reinterpret_cast<const float4*>(&hl[(n2 << 6) + c4]);
      v2.x *= s2; v2.y *= s2; v2.z *= s2; v2.w *= s2;
      *reinterpret_cast<float4*>(&hp[r2 * 64 + c4]) = v2;
    }
  }
#pragma unroll
  for (int u = 0; u < 7; ++u)
    if (ed[u] >= 0) {
      int a = lmap[es[u]], b = lmap[ed[u]];
      if ((a | b) >= 0) { es[u] = a; ed[u] = b; } else ed[u] = -1;
    }
  if (tid >= 512 && tid < 612) cur[tid - 512] = 0;
  __syncthreads();

  // ---- r1 sums + deg2 ----
  if (tid < 64) {
    float s = 0.f;
    for (int r = 0; r < 100; ++r) s += hp[r * 64 + tid];
    r1s[tid] = s;
  }
#pragma unroll
  for (int u = 0; u < 7; ++u)
    if (ed[u] >= 0) atomicAdd(&cur[ed[u]], 1);
  __syncthreads();

  // ---- scan2 (shfl, pad x4) ----
  {
    int d2 = 0, p2 = 0, v2s = 0;
    if (tid < 100) {
      d2 = cur[tid];
      p2 = (d2 + 3) & ~3;
      v2s = p2;
    }
#pragma unroll
    for (int o = 1; o < 64; o <<= 1) {
      int t = __shfl_up(v2s, o);
      if ((tid & 63) >= o) v2s += t;
    }
    if (tid < 100 && ((tid & 63) == 63 || tid == 99)) wpart[tid >> 6] = v2s;
    __syncthreads();
    if (tid < 100) {
      int base = (tid >= 64) ? wpart[0] : 0;
      int incl = base + v2s;
      dinv[tid] = 1.0f / sqrtf((float)d2 + 1.0f);
      off[tid + 1] = incl;
      cur[tid] = incl - p2;
      if (tid == 0) off[0] = 0;
    }
  }
  __syncthreads();
#pragma unroll
  for (int u = 0; u < 7; ++u)
    if (ed[u] >= 0) {
      int p = atomicAdd(&cur[ed[u]], 1);
      csr[p] = (unsigned short)(es[u] << 6);
    }
  __syncthreads();
  float* Ws = hl;                           // 4096 floats
  float* hl2 = hl + 4096;                   // 101 rows (row 100 = 0)
  float* hpost2 = hl + 4096 + 101 * 64;     // 100 rows
  if (tid < 100) {
    int pend = off[tid + 1];
    for (int p = cur[tid]; p < pend; ++p) csr[p] = (unsigned short)(100 * 64);
  }
  for (int i = tid; i < 4096; i += 1024) Ws[i] = W2[i];
  if (tid < 64) hl2[100 * 64 + tid] = 0.f;
  __syncthreads();

  // ---- gemm2: hl2 = dinv2 * (hp @ W2) ----
  {
    float acc[7];
#pragma unroll
    for (int p = 0; p < 7; ++p) acc[p] = 0.f;
    for (int kb = 0; kb < 64; kb += 4) {
      float w0  = Ws[(kb + 0) * 64 + lane];
      float w1  = Ws[(kb + 1) * 64 + lane];
      float w2v = Ws[(kb + 2) * 64 + lane];
      float w3v = Ws[(kb + 3) * 64 + lane];
#pragma unroll
      for (int p = 0; p < 7; ++p) {
        int n = wave + p * 16;
        if (n < 100) {
          float4 hv = *reinterpret_cast<const float4*>(&hp[n * 64 + kb]);
          acc[p] = fmaf(hv.x, w0, acc[p]);
          acc[p] = fmaf(hv.y, w1, acc[p]);
          acc[p] = fmaf(hv.z, w2v, acc[p]);
          acc[p] = fmaf(hv.w, w3v, acc[p]);
        }
      }
    }
#pragma unroll
    for (int p = 0; p < 7; ++p) {
      int n = wave + p * 16;
      if (n < 100) hl2[n * 64 + lane] = dinv[n] * acc[p];
    }
  }
  __syncthreads();

  // ---- gather2 + post + score ----
  {
    const float bc2 = b2[lane], pwc2 = pw2[lane];
#pragma unroll
    for (int it = 0; it < 7; ++it) {
      int n = wave + it * 16;
      if (n < 100) {
        float a0 = hl2[n * 64 + lane], a1 = 0.f;
        int e = off[n], end = off[n + 1];
        for (; e < end; e += 4) {
          uint2 pk = *reinterpret_cast<const uint2*>(&csr[e]);
          a0 += hl2[(pk.x & 0xFFFF) + lane];
          a1 += hl2[(pk.x >> 16) + lane];
          a0 += hl2[(pk.y & 0xFFFF) + lane];
          a1 += hl2[(pk.y >> 16) + lane];
        }
        float o = fmaxf(fmaf(a0 + a1, dinv[n], bc2), 0.f);
        hpost2[n * 64 + lane] = o;
        float sd = o * pwc2;
        sd += __shfl_xor(sd, 1);  sd += __shfl_xor(sd, 2);
        sd += __shfl_xor(sd, 4);  sd += __shfl_xor(sd, 8);
        sd += __shfl_xor(sd, 16); sd += __shfl_xor(sd, 32);
        if (lane == 0) sc[n] = tanhf(sd / nrm2_s);
      }
    }
  }
  __syncthreads();

  // ---- rank2 (2 nodes/thread, float4 broadcast) ----
  if (tid < 50) {
    int i0 = tid * 2, i1 = i0 + 1;
    float s0 = sc[i0], s1 = sc[i1];
    int rk0 = 0, rk1 = 0;
    for (int j4 = 0; j4 < 25; ++j4) {
      float4 sv = *reinterpret_cast<const float4*>(&sc[j4 * 4]);
      int jb = j4 * 4;
      rk0 += (sv.x > s0) || (sv.x == s0 && jb     < i0);
      rk0 += (sv.y > s0) || (sv.y == s0 && jb + 1 < i0);
      rk0 += (sv.z > s0) || (sv.z == s0 && jb + 2 < i0);
      rk0 += (sv.w > s0) || (sv.w == s0 && jb + 3 < i0);
      rk1 += (sv.x > s1) || (sv.x == s1 && jb     < i1);
      rk1 += (sv.y > s1) || (sv.y == s1 && jb + 1 < i1);
      rk1 += (sv.z > s1) || (sv.z == s1 && jb + 2 < i1);
      rk1 += (sv.w > s1) || (sv.w == s1 && jb + 3 < i1);
    }
    lmap[i0] = (rk0 < 25) ? rk0 : -1;
    if (rk0 < 25) sel[rk0] = i0;
    lmap[i1] = (rk1 < 25) ? rk1 : -1;
    if (rk1 < 25) sel[rk1] = i1;
  }
  __syncthreads();

  // ---- hp2 extract + remap + zero deg3 ----
  if (tid < 400) {
    int r = tid >> 4, c4 = (tid & 15) * 4;
    int n = sel[r];
    float s = sc[n];
    float4 vv = *reinterpret_cast<const float4*>(&hpost2[n * 64 + c4]);
    vv.x *= s; vv.y *= s; vv.z *= s; vv.w *= s;
    *reinterpret_cast<float4*>(&hp[r * 64 + c4]) = vv;
  }
#pragma unroll
  for (int u = 0; u < 7; ++u)
    if (ed[u] >= 0) {
      int a = lmap[es[u]], b = lmap[ed[u]];
      if ((a | b) >= 0) { es[u] = a; ed[u] = b; } else ed[u] = -1;
    }
  if (tid >= 512 && tid < 537) cur[tid - 512] = 0;
  __syncthreads();

  // ---- r2 sums + deg3 ----
  if (tid < 64) {
    float s = 0.f;
    for (int r = 0; r < 25; ++r) s += hp[r * 64 + tid];
    r2s[tid] = s;
  }
#pragma unroll
  for (int u = 0; u < 7; ++u)
    if (ed[u] >= 0) atomicAdd(&cur[ed[u]], 1);
  __syncthreads();

  // ---- scan3 (single-wave shfl, pad x4) ----
  {
    int d3 = 0, p3 = 0, v3s = 0;
    if (tid < 25) {
      d3 = cur[tid];
      p3 = (d3 + 3) & ~3;
      v3s = p3;
    }
    if (tid < 64) {
#pragma unroll
      for (int o = 1; o < 32; o <<= 1) {
        int t = __shfl_up(v3s, o);
        if (lane >= o) v3s += t;
      }
    }
    __syncthreads();
    if (tid < 25) {
      dinv[tid] = 1.0f / sqrtf((float)d3 + 1.0f);
      off[tid + 1] = v3s;
      cur[tid] = v3s - p3;
      if (tid == 0) off[0] = 0;
    }
  }
  __syncthreads();
#pragma unroll
  for (int u = 0; u < 7; ++u)
    if (ed[u] >= 0) {
      int p = atomicAdd(&cur[ed[u]], 1);
      csr[p] = (unsigned short)(es[u] << 6);
    }
  __syncthreads();
  float* hl3 = hl + 4096;                   // 26 rows (row 25 = 0)
  if (tid < 25) {
    int pend = off[tid + 1];
    for (int p = cur[tid]; p < pend; ++p) csr[p] = (unsigned short)(25 * 64);
  }
  for (int i = tid; i < 4096; i += 1024) Ws[i] = W3[i];
  if (tid < 64) hl3[25 * 64 + tid] = 0.f;
  __syncthreads();

  // ---- gemm3 (P=2) ----
  {
    float a0c = 0.f, a1c = 0.f;
    const int n1 = wave + 16;
    for (int kb = 0; kb < 64; kb += 4) {
      float w0  = Ws[(kb + 0) * 64 + lane];
      float w1  = Ws[(kb + 1) * 64 + lane];
      float w2v = Ws[(kb + 2) * 64 + lane];
      float w3v = Ws[(kb + 3) * 64 + lane];
      {
        float4 hv = *reinterpret_cast<const float4*>(&hp[wave * 64 + kb]);
        a0c = fmaf(hv.x, w0, a0c);
        a0c = fmaf(hv.y, w1, a0c);
        a0c = fmaf(hv.z, w2v, a0c);
        a0c = fmaf(hv.w, w3v, a0c);
      }
      if (n1 < 25) {
        float4 hv = *reinterpret_cast<const float4*>(&hp[n1 * 64 + kb]);
        a1c = fmaf(hv.x, w0, a1c);
        a1c = fmaf(hv.y, w1, a1c);
        a1c = fmaf(hv.z, w2v, a1c);
        a1c = fmaf(hv.w, w3v, a1c);
      }
    }
    hl3[wave * 64 + lane] = dinv[wave] * a0c;
    if (n1 < 25) hl3[n1 * 64 + lane] = dinv[n1] * a1c;
  }
  __syncthreads();

  // ---- gather3 + r3 partials ----
  {
    const float bc3 = b3[lane];
    float part = 0.f;
#pragma unroll
    for (int it = 0; it < 2; ++it) {
      int n = wave + it * 16;
      if (n < 25) {
        float a0 = hl3[n * 64 + lane], a1 = 0.f;
        int e = off[n], end = off[n + 1];
        for (; e < end; e += 4) {
          uint2 pk = *reinterpret_cast<const uint2*>(&csr[e]);
          a0 += hl3[(pk.x & 0xFFFF) + lane];
          a1 += hl3[(pk.x >> 16) + lane];
          a0 += hl3[(pk.y & 0xFFFF) + lane];
          a1 += hl3[(pk.y >> 16) + lane];
        }
        part += fmaxf(fmaf(a0 + a1, dinv[n], bc3), 0.f);
      }
    }
    float* red = hl + 8192;
    red[wave * 64 + lane] = part;
  }
  __syncthreads();

  // ---- final linear ----
  if (tid < 64) {
    float* red = hl + 8192;
    float r3c = 0.f;
#pragma unroll
    for (int w = 0; w < 16; ++w) r3c += red[w * 64 + tid];
    float f1 = r2s[tid], f2 = r1s[tid];
    float p0 = r3c * Wl[tid * 2 + 0] + f1 * Wl[(64 + tid) * 2 + 0] + f2 * Wl[(128 + tid) * 2 + 0];
    float p1 = r3c * Wl[tid * 2 + 1] + f1 * Wl[(64 + tid) * 2 + 1] + f2 * Wl[(128 + tid) * 2 + 1];
#pragma unroll
    for (int o = 32; o; o >>= 1) {
      p0 += __shfl_xor(p0, o);
      p1 += __shfl_xor(p1, o);
    }
    if (tid == 0) {
      out[g * 2 + 0] = p0 + bl[0];
      out[g * 2 + 1] = p1 + bl[1];
    }
  }
}

// ---------------------------------------------------------------------------
extern "C" void kernel_launch(void* const* d_in, const int* in_sizes, int n_in,
                              void* d_out, int out_size, void* d_ws, size_t ws_size,
                              hipStream_t stream) {
  const float* x   = (const float*)d_in[0];
  const int*   src = (const int*)d_in[1];
  const int*   dst = (const int*)d_in[2];
  const float* W1  = (const float*)d_in[4];
  const float* b1  = (const float*)d_in[5];
  const float* W2  = (const float*)d_in[6];
  const float* b2  = (const float*)d_in[7];
  const float* W3  = (const float*)d_in[8];
  const float* b3  = (const float*)d_in[9];
  const float* pw1 = (const float*)d_in[10];
  const float* pw2 = (const float*)d_in[11];
  const float* Wl  = (const float*)d_in[12];
  const float* bl  = (const float*)d_in[13];
  float* out = (float*)d_out;

  float* h1 = (float*)d_ws;   // 102400 x 64 floats

  gemm64x<128><<<dim3(BGR, 7), 256, 0, stream>>>(x, W1, h1);
  mega<<<BGR, 1024, 0, stream>>>(h1, src, dst, b1, pw1, W2, b2, pw2,
                                 W3, b3, Wl, bl, out);
}